// Round 1
// baseline (680.801 us; speedup 1.0000x reference)
//
#include <hip/hip_runtime.h>
#include <hip/hip_bf16.h>
#include <stdint.h>

typedef __bf16 bf16_t;
typedef __bf16 bf16x4 __attribute__((ext_vector_type(4)));
typedef __bf16 bf16x8 __attribute__((ext_vector_type(8)));
typedef float  f32x4  __attribute__((ext_vector_type(4)));

#define MFMA16(a, b, c) __builtin_amdgcn_mfma_f32_16x16x32_bf16((a), (b), (c), 0, 0, 0)

static constexpr int TOKS   = 16384;  // B*N
static constexpr int SEQ    = 4096;
static constexpr int DIMK   = 1024;
static constexpr int H2     = 4096;   // 2*HIDDEN
static constexpr int HID    = 2048;
static constexpr int QKD    = 128;
static constexpr int NTILES = 528;    // causal 128x128 tiles per batch: 32*33/2

// async global->LDS, 16B per lane; LDS dest must be wave-uniform base (+lane*16 by HW)
__device__ __forceinline__ void gload_lds16(const bf16_t* g, bf16_t* l) {
  __builtin_amdgcn_global_load_lds((__attribute__((address_space(1))) void*)(g),
                                   (__attribute__((address_space(3))) void*)(l),
                                   16, 0, 0);
}

__device__ __forceinline__ float silu_f(float v) { return v / (1.0f + __expf(-v)); }

// ---------------------------------------------------------------------------
// Weight transpose + f32->bf16:  W[K][N] f32  ->  WT[N][K] bf16
// ---------------------------------------------------------------------------
__global__ __launch_bounds__(256) void k_transpose_bf16(const float* __restrict__ W,
                                                        bf16_t* __restrict__ WT,
                                                        int K, int N) {
  __shared__ float t[32][33];
  int n0 = blockIdx.x * 32, k0 = blockIdx.y * 32;
  int tx = threadIdx.x & 31, ty = threadIdx.x >> 5;  // 32 x 8
#pragma unroll
  for (int r = 0; r < 32; r += 8)
    t[ty + r][tx] = W[(size_t)(k0 + ty + r) * N + n0 + tx];
  __syncthreads();
#pragma unroll
  for (int r = 0; r < 32; r += 8)
    WT[(size_t)(n0 + ty + r) * K + k0 + tx] = (bf16_t)t[tx][ty + r];
}

// ---------------------------------------------------------------------------
// LayerNorm: x[16384][1024] f32 -> normed bf16
// ---------------------------------------------------------------------------
__global__ __launch_bounds__(256) void k_layernorm(const float* __restrict__ x,
                                                   const float* __restrict__ g,
                                                   const float* __restrict__ b,
                                                   bf16_t* __restrict__ out) {
  int row = blockIdx.x, t = threadIdx.x;
  const float4* xr = (const float4*)(x + (size_t)row * DIMK);
  float4 v = xr[t];
  float s  = v.x + v.y + v.z + v.w;
  float ss = v.x * v.x + v.y * v.y + v.z * v.z + v.w * v.w;
#pragma unroll
  for (int o = 1; o < 64; o <<= 1) { s += __shfl_xor(s, o); ss += __shfl_xor(ss, o); }
  __shared__ float red[8];
  int wave = t >> 6, lane = t & 63;
  if (lane == 0) { red[wave] = s; red[wave + 4] = ss; }
  __syncthreads();
  s  = red[0] + red[1] + red[2] + red[3];
  ss = red[4] + red[5] + red[6] + red[7];
  float mean = s * (1.0f / DIMK);
  float var  = ss * (1.0f / DIMK) - mean * mean;
  float rstd = rsqrtf(var + 1e-5f);
  float4 gg = ((const float4*)g)[t];
  float4 bb = ((const float4*)b)[t];
  bf16x4 o4;
  o4[0] = (bf16_t)((v.x - mean) * rstd * gg.x + bb.x);
  o4[1] = (bf16_t)((v.y - mean) * rstd * gg.y + bb.y);
  o4[2] = (bf16_t)((v.z - mean) * rstd * gg.z + bb.z);
  o4[3] = (bf16_t)((v.w - mean) * rstd * gg.w + bb.w);
  *(bf16x4*)(out + (size_t)row * DIMK + t * 4) = o4;
}

// ---------------------------------------------------------------------------
// Shared 128x128 GEMM core (m97 structure): A row-major [M][K], BT row-major
// [N][K]. 256 threads / 4 waves; wave tile 64x64; BK=32; 16 MFMA per K-step.
// Fragment maps (verified m91+): A: a[e]=A[lane&15][(lane>>4)*8+e];
// B: b[e]=BT[lane&15][(lane>>4)*8+e]; D: d[r]=D[(lane>>4)*4+r][lane&15].
// Ag0/Bg0 are per-lane pointers with row = wave*32+(lane>>2), kofs=(lane&3)*8 baked.
// ---------------------------------------------------------------------------
__device__ __forceinline__ void gemm_core_std(const bf16_t* __restrict__ Ag0, int lda,
                                              const bf16_t* __restrict__ Bg0, int ldb,
                                              int K, bf16_t* As, bf16_t* Bs,
                                              f32x4 acc[4][4]) {
  const int tid = threadIdx.x;
  const int wave = tid >> 6, lane = tid & 63;
  bf16_t* asw = As + wave * 32 * 32;
  bf16_t* bsw = Bs + wave * 32 * 32;
  const int ar = ((wave >> 1) * 64 + (lane & 15)) * 32 + (lane >> 4) * 8;
  const int br = ((wave & 1) * 64 + (lane & 15)) * 32 + (lane >> 4) * 8;
  for (int k0 = 0; k0 < K; k0 += 32) {
    __syncthreads();  // prev-iter LDS reads done
    gload_lds16(Ag0 + k0, asw);
    gload_lds16(Ag0 + k0 + 16 * lda, asw + 16 * 32);
    gload_lds16(Bg0 + k0, bsw);
    gload_lds16(Bg0 + k0 + 16 * ldb, bsw + 16 * 32);
    __syncthreads();  // staging visible (vmcnt(0) drained by barrier)
    bf16x8 af[4], bfr[4];
#pragma unroll
    for (int m = 0; m < 4; m++) af[m] = *(const bf16x8*)(As + ar + m * 16 * 32);
#pragma unroll
    for (int n = 0; n < 4; n++) bfr[n] = *(const bf16x8*)(Bs + br + n * 16 * 32);
#pragma unroll
    for (int m = 0; m < 4; m++)
#pragma unroll
      for (int n = 0; n < 4; n++) acc[m][n] = MFMA16(af[m], bfr[n], acc[m][n]);
  }
}

// ---------------------------------------------------------------------------
// GEMM1: silu(normed @ Wh + bh) -> vT[2048][16384] (transposed) / gate[16384][2048]
// ---------------------------------------------------------------------------
__global__ __launch_bounds__(256) void k_gemm_hidden(const bf16_t* __restrict__ A,
                                                     const bf16_t* __restrict__ BT,
                                                     const float* __restrict__ bias,
                                                     bf16_t* __restrict__ vT,
                                                     bf16_t* __restrict__ gate) {
  __shared__ __align__(16) bf16_t As[128 * 32];
  __shared__ __align__(16) bf16_t Bs[128 * 32];
  const int tid = threadIdx.x, wave = tid >> 6, lane = tid & 63;
  const int m0 = blockIdx.y * 128, n0 = blockIdx.x * 128;
  const bf16_t* Ag0 = A + (size_t)(m0 + wave * 32 + (lane >> 2)) * DIMK + (lane & 3) * 8;
  const bf16_t* Bg0 = BT + (size_t)(n0 + wave * 32 + (lane >> 2)) * DIMK + (lane & 3) * 8;
  f32x4 acc[4][4];
#pragma unroll
  for (int m = 0; m < 4; m++)
#pragma unroll
    for (int n = 0; n < 4; n++) acc[m][n] = (f32x4){0.f, 0.f, 0.f, 0.f};
  gemm_core_std(Ag0, DIMK, Bg0, DIMK, DIMK, As, Bs, acc);

  const int row0 = m0 + (wave >> 1) * 64;
  const int col0 = n0 + (wave & 1) * 64;
#pragma unroll
  for (int m = 0; m < 4; m++) {
#pragma unroll
    for (int n = 0; n < 4; n++) {
      int col = col0 + n * 16 + (lane & 15);
      float bv = bias[col];
      int row = row0 + m * 16 + ((lane >> 4) << 2);
      float sv[4];
#pragma unroll
      for (int r = 0; r < 4; r++) sv[r] = silu_f(acc[m][n][r] + bv);
      if (col < HID) {  // v half -> transposed, 4 consecutive tokens pack to 8B
        bf16x4 pk;
#pragma unroll
        for (int r = 0; r < 4; r++) pk[r] = (bf16_t)sv[r];
        *(bf16x4*)(vT + (size_t)col * TOKS + row) = pk;
      } else {          // gate half -> row-major
#pragma unroll
        for (int r = 0; r < 4; r++)
          gate[(size_t)(row + r) * HID + (col - HID)] = (bf16_t)sv[r];
      }
    }
  }
}

// ---------------------------------------------------------------------------
// qk GEMM: qkv = silu(normed @ Wqk + bqk); q/k = qkv*gamma+beta (bf16)
// ---------------------------------------------------------------------------
__global__ __launch_bounds__(256) void k_gemm_qk(const bf16_t* __restrict__ A,
                                                 const bf16_t* __restrict__ BT,
                                                 const float* __restrict__ bias,
                                                 const float* __restrict__ osg,
                                                 const float* __restrict__ osb,
                                                 bf16_t* __restrict__ qo,
                                                 bf16_t* __restrict__ ko) {
  __shared__ __align__(16) bf16_t As[128 * 32];
  __shared__ __align__(16) bf16_t Bs[128 * 32];
  const int tid = threadIdx.x, wave = tid >> 6, lane = tid & 63;
  const int m0 = blockIdx.y * 128;
  const bf16_t* Ag0 = A + (size_t)(m0 + wave * 32 + (lane >> 2)) * DIMK + (lane & 3) * 8;
  const bf16_t* Bg0 = BT + (size_t)(wave * 32 + (lane >> 2)) * DIMK + (lane & 3) * 8;
  f32x4 acc[4][4];
#pragma unroll
  for (int m = 0; m < 4; m++)
#pragma unroll
    for (int n = 0; n < 4; n++) acc[m][n] = (f32x4){0.f, 0.f, 0.f, 0.f};
  gemm_core_std(Ag0, DIMK, Bg0, DIMK, DIMK, As, Bs, acc);

  const int row0 = m0 + (wave >> 1) * 64;
  const int col0 = (wave & 1) * 64;
#pragma unroll
  for (int m = 0; m < 4; m++) {
#pragma unroll
    for (int n = 0; n < 4; n++) {
      int col = col0 + n * 16 + (lane & 15);
      float bv = bias[col];
      float g0 = osg[col], b0 = osb[col];
      float g1 = osg[QKD + col], b1 = osb[QKD + col];
      int row = row0 + m * 16 + ((lane >> 4) << 2);
#pragma unroll
      for (int r = 0; r < 4; r++) {
        float sv = silu_f(acc[m][n][r] + bv);
        qo[(size_t)(row + r) * QKD + col] = (bf16_t)(sv * g0 + b0);
        ko[(size_t)(row + r) * QKD + col] = (bf16_t)(sv * g1 + b1);
      }
    }
  }
}

// ---------------------------------------------------------------------------
// Pass A: P tile (ib,jb) = relu( (q@k^T)/(i+1) )^2, causal-masked, bf16,
// packed-triangular storage: tile index = bb*528 + ib*(ib+1)/2 + jb
// ---------------------------------------------------------------------------
__global__ __launch_bounds__(256) void k_qkt(const bf16_t* __restrict__ qb,
                                             const bf16_t* __restrict__ kb,
                                             bf16_t* __restrict__ Pb) {
  const int jb = blockIdx.x, ib = blockIdx.y, bb = blockIdx.z;
  if (jb > ib) return;
  __shared__ __align__(16) bf16_t As[128 * 32];
  __shared__ __align__(16) bf16_t Bs[128 * 32];
  const int tid = threadIdx.x, wave = tid >> 6, lane = tid & 63;
  const bf16_t* Ag0 = qb + (size_t)(bb * SEQ + ib * 128 + wave * 32 + (lane >> 2)) * QKD + (lane & 3) * 8;
  const bf16_t* Bg0 = kb + (size_t)(bb * SEQ + jb * 128 + wave * 32 + (lane >> 2)) * QKD + (lane & 3) * 8;
  f32x4 acc[4][4];
#pragma unroll
  for (int m = 0; m < 4; m++)
#pragma unroll
    for (int n = 0; n < 4; n++) acc[m][n] = (f32x4){0.f, 0.f, 0.f, 0.f};
  gemm_core_std(Ag0, QKD, Bg0, QKD, QKD, As, Bs, acc);

  size_t tb = ((size_t)bb * NTILES + (size_t)ib * (ib + 1) / 2 + jb) * 16384;
  const int il0 = (wave >> 1) * 64, jl0 = (wave & 1) * 64;
#pragma unroll
  for (int m = 0; m < 4; m++) {
#pragma unroll
    for (int n = 0; n < 4; n++) {
      int jloc = jl0 + n * 16 + (lane & 15);
      int jg = jb * 128 + jloc;
#pragma unroll
      for (int r = 0; r < 4; r++) {
        int iloc = il0 + m * 16 + ((lane >> 4) << 2) + r;
        int ig = ib * 128 + iloc;
        float sv = acc[m][n][r] / (float)(ig + 1);
        sv = fmaxf(sv, 0.f);
        sv *= sv;
        if (jg > ig) sv = 0.f;
        Pb[tb + (size_t)iloc * 128 + jloc] = (bf16_t)sv;
      }
    }
  }
}

// ---------------------------------------------------------------------------
// Pass B: out = P @ v (variable causal K), epilogue: *= gate, written in place
// over gate buffer (each element read-then-written by its own thread only).
// A tiles come from packed P storage (lda=128 within a 32KB tile).
// ---------------------------------------------------------------------------
__global__ __launch_bounds__(256) void k_pv(const bf16_t* __restrict__ Pb,
                                            const bf16_t* __restrict__ vT,
                                            bf16_t* __restrict__ gate) {
  const int hb = blockIdx.x, ib = blockIdx.y, bb = blockIdx.z;
  const int K = (ib + 1) * 128;
  __shared__ __align__(16) bf16_t As[128 * 32];
  __shared__ __align__(16) bf16_t Bs[128 * 32];
  const int tid = threadIdx.x, wave = tid >> 6, lane = tid & 63;
  bf16_t* asw = As + wave * 32 * 32;
  bf16_t* bsw = Bs + wave * 32 * 32;
  const size_t tb = ((size_t)bb * NTILES + (size_t)ib * (ib + 1) / 2) * 16384;
  const int arow = wave * 32 + (lane >> 2);
  const bf16_t* Bg0 = vT + (size_t)(hb * 128 + wave * 32 + (lane >> 2)) * TOKS + bb * SEQ + (lane & 3) * 8;
  const int ar = ((wave >> 1) * 64 + (lane & 15)) * 32 + (lane >> 4) * 8;
  const int br = ((wave & 1) * 64 + (lane & 15)) * 32 + (lane >> 4) * 8;
  f32x4 acc[4][4];
#pragma unroll
  for (int m = 0; m < 4; m++)
#pragma unroll
    for (int n = 0; n < 4; n++) acc[m][n] = (f32x4){0.f, 0.f, 0.f, 0.f};

  for (int k0 = 0; k0 < K; k0 += 32) {
    __syncthreads();
    const bf16_t* At = Pb + tb + (size_t)(k0 >> 7) * 16384 + (k0 & 127) + (lane & 3) * 8;
    gload_lds16(At + arow * 128, asw);
    gload_lds16(At + (arow + 16) * 128, asw + 16 * 32);
    gload_lds16(Bg0 + k0, bsw);
    gload_lds16(Bg0 + k0 + 16 * TOKS, bsw + 16 * 32);
    __syncthreads();
    bf16x8 af[4], bfr[4];
#pragma unroll
    for (int m = 0; m < 4; m++) af[m] = *(const bf16x8*)(As + ar + m * 16 * 32);
#pragma unroll
    for (int n = 0; n < 4; n++) bfr[n] = *(const bf16x8*)(Bs + br + n * 16 * 32);
#pragma unroll
    for (int m = 0; m < 4; m++)
#pragma unroll
      for (int n = 0; n < 4; n++) acc[m][n] = MFMA16(af[m], bfr[n], acc[m][n]);
  }

  const int row0 = ib * 128 + (wave >> 1) * 64;
  const int col0 = hb * 128 + (wave & 1) * 64;
#pragma unroll
  for (int m = 0; m < 4; m++) {
#pragma unroll
    for (int n = 0; n < 4; n++) {
      int col = col0 + n * 16 + (lane & 15);
      int row = row0 + m * 16 + ((lane >> 4) << 2);
#pragma unroll
      for (int r = 0; r < 4; r++) {
        size_t gi = (size_t)(bb * SEQ + row + r) * HID + col;
        float gv = (float)gate[gi];
        gate[gi] = (bf16_t)(acc[m][n][r] * gv);
      }
    }
  }
}

// ---------------------------------------------------------------------------
// Final GEMM: out = gated @ Wo + bo + x   (fp32 out, fp32 residual)
// ---------------------------------------------------------------------------
__global__ __launch_bounds__(256) void k_gemm_out(const bf16_t* __restrict__ A,
                                                  const bf16_t* __restrict__ BT,
                                                  const float* __restrict__ bo,
                                                  const float* __restrict__ x,
                                                  float* __restrict__ out) {
  __shared__ __align__(16) bf16_t As[128 * 32];
  __shared__ __align__(16) bf16_t Bs[128 * 32];
  const int tid = threadIdx.x, wave = tid >> 6, lane = tid & 63;
  const int m0 = blockIdx.y * 128, n0 = blockIdx.x * 128;
  const bf16_t* Ag0 = A + (size_t)(m0 + wave * 32 + (lane >> 2)) * HID + (lane & 3) * 8;
  const bf16_t* Bg0 = BT + (size_t)(n0 + wave * 32 + (lane >> 2)) * HID + (lane & 3) * 8;
  f32x4 acc[4][4];
#pragma unroll
  for (int m = 0; m < 4; m++)
#pragma unroll
    for (int n = 0; n < 4; n++) acc[m][n] = (f32x4){0.f, 0.f, 0.f, 0.f};
  gemm_core_std(Ag0, HID, Bg0, HID, HID, As, Bs, acc);

  const int row0 = m0 + (wave >> 1) * 64;
  const int col0 = n0 + (wave & 1) * 64;
#pragma unroll
  for (int m = 0; m < 4; m++) {
#pragma unroll
    for (int n = 0; n < 4; n++) {
      int col = col0 + n * 16 + (lane & 15);
      float bv = bo[col];
      int row = row0 + m * 16 + ((lane >> 4) << 2);
#pragma unroll
      for (int r = 0; r < 4; r++) {
        size_t gi = (size_t)(row + r) * DIMK + col;
        out[gi] = acc[m][n][r] + bv + x[gi];
      }
    }
  }
}

// ---------------------------------------------------------------------------
extern "C" void kernel_launch(void* const* d_in, const int* in_sizes, int n_in,
                              void* d_out, int out_size, void* d_ws, size_t ws_size,
                              hipStream_t stream) {
  (void)in_sizes; (void)n_in; (void)out_size; (void)ws_size;
  const float* x    = (const float*)d_in[0];
  const float* ln_g = (const float*)d_in[1];
  const float* ln_b = (const float*)d_in[2];
  const float* Wh   = (const float*)d_in[3];
  const float* bh   = (const float*)d_in[4];
  const float* Wqk  = (const float*)d_in[5];
  const float* bqk  = (const float*)d_in[6];
  const float* osg  = (const float*)d_in[7];
  const float* osb  = (const float*)d_in[8];
  const float* Wo   = (const float*)d_in[9];
  const float* bo   = (const float*)d_in[10];
  float* out = (float*)d_out;

  char* ws = (char*)d_ws;
  bf16_t* normed = (bf16_t*)ws;  ws += (size_t)TOKS * DIMK * 2;   // 32 MB
  bf16_t* WhT    = (bf16_t*)ws;  ws += (size_t)H2 * DIMK * 2;     // 8 MB
  bf16_t* WqkT   = (bf16_t*)ws;  ws += (size_t)QKD * DIMK * 2;    // 0.25 MB
  bf16_t* WoT    = (bf16_t*)ws;  ws += (size_t)DIMK * HID * 2;    // 4 MB
  bf16_t* gate   = (bf16_t*)ws;  ws += (size_t)TOKS * HID * 2;    // 64 MB (becomes gated)
  bf16_t* vT     = (bf16_t*)ws;  ws += (size_t)HID * TOKS * 2;    // 64 MB
  bf16_t* qb     = (bf16_t*)ws;  ws += (size_t)TOKS * QKD * 2;    // 4 MB
  bf16_t* kb     = (bf16_t*)ws;  ws += (size_t)TOKS * QKD * 2;    // 4 MB
  bf16_t* Pb     = (bf16_t*)ws;  ws += (size_t)4 * NTILES * 16384 * 2;  // 66 MB

  k_transpose_bf16<<<dim3(H2 / 32, DIMK / 32), 256, 0, stream>>>(Wh, WhT, DIMK, H2);
  k_transpose_bf16<<<dim3(QKD / 32, DIMK / 32), 256, 0, stream>>>(Wqk, WqkT, DIMK, QKD);
  k_transpose_bf16<<<dim3(DIMK / 32, HID / 32), 256, 0, stream>>>(Wo, WoT, HID, DIMK);
  k_layernorm<<<TOKS, 256, 0, stream>>>(x, ln_g, ln_b, normed);
  k_gemm_hidden<<<dim3(H2 / 128, TOKS / 128), 256, 0, stream>>>(normed, WhT, bh, vT, gate);
  k_gemm_qk<<<dim3(1, TOKS / 128), 256, 0, stream>>>(normed, WqkT, bqk, osg, osb, qb, kb);
  k_qkt<<<dim3(SEQ / 128, SEQ / 128, 4), 256, 0, stream>>>(qb, kb, Pb);
  k_pv<<<dim3(HID / 128, SEQ / 128, 4), 256, 0, stream>>>(Pb, vT, gate);
  k_gemm_out<<<dim3(DIMK / 128, TOKS / 128), 256, 0, stream>>>(gate, WoT, bo, x, out);
}

// Round 2
// 589.052 us; speedup vs baseline: 1.1558x; 1.1558x over previous
//
#include <hip/hip_runtime.h>
#include <hip/hip_bf16.h>
#include <stdint.h>

typedef __bf16 bf16_t;
typedef __bf16 bf16x4 __attribute__((ext_vector_type(4)));
typedef __bf16 bf16x8 __attribute__((ext_vector_type(8)));
typedef float  f32x4  __attribute__((ext_vector_type(4)));

#define MFMA16(a, b, c) __builtin_amdgcn_mfma_f32_16x16x32_bf16((a), (b), (c), 0, 0, 0)

static constexpr int TOKS   = 16384;  // B*N
static constexpr int SEQ    = 4096;
static constexpr int DIMK   = 1024;
static constexpr int H2     = 4096;   // 2*HIDDEN
static constexpr int HID    = 2048;
static constexpr int QKD    = 128;
static constexpr int NTILES = 528;    // causal 128x128 tiles per batch: 32*33/2

// async global->LDS, 16B per lane; LDS dest must be wave-uniform base (+lane*16 by HW)
__device__ __forceinline__ void gload_lds16(const bf16_t* g, bf16_t* l) {
  __builtin_amdgcn_global_load_lds((__attribute__((address_space(1))) void*)(g),
                                   (__attribute__((address_space(3))) void*)(l),
                                   16, 0, 0);
}

__device__ __forceinline__ float silu_f(float v) { return v / (1.0f + __expf(-v)); }

// ---------------------------------------------------------------------------
// Weight transpose + f32->bf16:  W[K][N] f32  ->  WT[N][K] bf16
// ---------------------------------------------------------------------------
__global__ __launch_bounds__(256) void k_transpose_bf16(const float* __restrict__ W,
                                                        bf16_t* __restrict__ WT,
                                                        int K, int N) {
  __shared__ float t[32][33];
  int n0 = blockIdx.x * 32, k0 = blockIdx.y * 32;
  int tx = threadIdx.x & 31, ty = threadIdx.x >> 5;  // 32 x 8
#pragma unroll
  for (int r = 0; r < 32; r += 8)
    t[ty + r][tx] = W[(size_t)(k0 + ty + r) * N + n0 + tx];
  __syncthreads();
#pragma unroll
  for (int r = 0; r < 32; r += 8)
    WT[(size_t)(n0 + ty + r) * K + k0 + tx] = (bf16_t)t[tx][ty + r];
}

// ---------------------------------------------------------------------------
// LayerNorm: x[16384][1024] f32 -> normed bf16
// ---------------------------------------------------------------------------
__global__ __launch_bounds__(256) void k_layernorm(const float* __restrict__ x,
                                                   const float* __restrict__ g,
                                                   const float* __restrict__ b,
                                                   bf16_t* __restrict__ out) {
  int row = blockIdx.x, t = threadIdx.x;
  const float4* xr = (const float4*)(x + (size_t)row * DIMK);
  float4 v = xr[t];
  float s  = v.x + v.y + v.z + v.w;
  float ss = v.x * v.x + v.y * v.y + v.z * v.z + v.w * v.w;
#pragma unroll
  for (int o = 1; o < 64; o <<= 1) { s += __shfl_xor(s, o); ss += __shfl_xor(ss, o); }
  __shared__ float red[8];
  int wave = t >> 6, lane = t & 63;
  if (lane == 0) { red[wave] = s; red[wave + 4] = ss; }
  __syncthreads();
  s  = red[0] + red[1] + red[2] + red[3];
  ss = red[4] + red[5] + red[6] + red[7];
  float mean = s * (1.0f / DIMK);
  float var  = ss * (1.0f / DIMK) - mean * mean;
  float rstd = rsqrtf(var + 1e-5f);
  float4 gg = ((const float4*)g)[t];
  float4 bb = ((const float4*)b)[t];
  bf16x4 o4;
  o4[0] = (bf16_t)((v.x - mean) * rstd * gg.x + bb.x);
  o4[1] = (bf16_t)((v.y - mean) * rstd * gg.y + bb.y);
  o4[2] = (bf16_t)((v.z - mean) * rstd * gg.z + bb.z);
  o4[3] = (bf16_t)((v.w - mean) * rstd * gg.w + bb.w);
  *(bf16x4*)(out + (size_t)row * DIMK + t * 4) = o4;
}

// ---------------------------------------------------------------------------
// Shared 128x128 GEMM core (m97 structure): A row-major [M][K], BT row-major
// [N][K]. 256 threads / 4 waves; wave tile 64x64; BK=32; 16 MFMA per K-step.
// ---------------------------------------------------------------------------
__device__ __forceinline__ void gemm_core_std(const bf16_t* __restrict__ Ag0, int lda,
                                              const bf16_t* __restrict__ Bg0, int ldb,
                                              int K, bf16_t* As, bf16_t* Bs,
                                              f32x4 acc[4][4]) {
  const int tid = threadIdx.x;
  const int wave = tid >> 6, lane = tid & 63;
  bf16_t* asw = As + wave * 32 * 32;
  bf16_t* bsw = Bs + wave * 32 * 32;
  const int ar = ((wave >> 1) * 64 + (lane & 15)) * 32 + (lane >> 4) * 8;
  const int br = ((wave & 1) * 64 + (lane & 15)) * 32 + (lane >> 4) * 8;
  for (int k0 = 0; k0 < K; k0 += 32) {
    __syncthreads();  // prev-iter LDS reads done
    gload_lds16(Ag0 + k0, asw);
    gload_lds16(Ag0 + k0 + 16 * lda, asw + 16 * 32);
    gload_lds16(Bg0 + k0, bsw);
    gload_lds16(Bg0 + k0 + 16 * ldb, bsw + 16 * 32);
    __syncthreads();  // staging visible
    bf16x8 af[4], bfr[4];
#pragma unroll
    for (int m = 0; m < 4; m++) af[m] = *(const bf16x8*)(As + ar + m * 16 * 32);
#pragma unroll
    for (int n = 0; n < 4; n++) bfr[n] = *(const bf16x8*)(Bs + br + n * 16 * 32);
#pragma unroll
    for (int m = 0; m < 4; m++)
#pragma unroll
      for (int n = 0; n < 4; n++) acc[m][n] = MFMA16(af[m], bfr[n], acc[m][n]);
  }
}

// ---------------------------------------------------------------------------
// GEMM1: silu(normed @ Wh + bh) -> vT[2048][16384] (transposed) / gate[16384][2048]
// ---------------------------------------------------------------------------
__global__ __launch_bounds__(256) void k_gemm_hidden(const bf16_t* __restrict__ A,
                                                     const bf16_t* __restrict__ BT,
                                                     const float* __restrict__ bias,
                                                     bf16_t* __restrict__ vT,
                                                     bf16_t* __restrict__ gate) {
  __shared__ __align__(16) bf16_t As[128 * 32];
  __shared__ __align__(16) bf16_t Bs[128 * 32];
  const int tid = threadIdx.x, wave = tid >> 6, lane = tid & 63;
  const int m0 = blockIdx.y * 128, n0 = blockIdx.x * 128;
  const bf16_t* Ag0 = A + (size_t)(m0 + wave * 32 + (lane >> 2)) * DIMK + (lane & 3) * 8;
  const bf16_t* Bg0 = BT + (size_t)(n0 + wave * 32 + (lane >> 2)) * DIMK + (lane & 3) * 8;
  f32x4 acc[4][4];
#pragma unroll
  for (int m = 0; m < 4; m++)
#pragma unroll
    for (int n = 0; n < 4; n++) acc[m][n] = (f32x4){0.f, 0.f, 0.f, 0.f};
  gemm_core_std(Ag0, DIMK, Bg0, DIMK, DIMK, As, Bs, acc);

  const int row0 = m0 + (wave >> 1) * 64;
  const int col0 = n0 + (wave & 1) * 64;
#pragma unroll
  for (int m = 0; m < 4; m++) {
#pragma unroll
    for (int n = 0; n < 4; n++) {
      int col = col0 + n * 16 + (lane & 15);
      float bv = bias[col];
      int row = row0 + m * 16 + ((lane >> 4) << 2);
      float sv[4];
#pragma unroll
      for (int r = 0; r < 4; r++) sv[r] = silu_f(acc[m][n][r] + bv);
      if (col < HID) {  // v half -> transposed, 4 consecutive tokens pack to 8B
        bf16x4 pk;
#pragma unroll
        for (int r = 0; r < 4; r++) pk[r] = (bf16_t)sv[r];
        *(bf16x4*)(vT + (size_t)col * TOKS + row) = pk;
      } else {          // gate half -> row-major
#pragma unroll
        for (int r = 0; r < 4; r++)
          gate[(size_t)(row + r) * HID + (col - HID)] = (bf16_t)sv[r];
      }
    }
  }
}

// ---------------------------------------------------------------------------
// qk GEMM: qkv = silu(normed @ Wqk + bqk); q/k = qkv*gamma+beta (bf16)
// ---------------------------------------------------------------------------
__global__ __launch_bounds__(256) void k_gemm_qk(const bf16_t* __restrict__ A,
                                                 const bf16_t* __restrict__ BT,
                                                 const float* __restrict__ bias,
                                                 const float* __restrict__ osg,
                                                 const float* __restrict__ osb,
                                                 bf16_t* __restrict__ qo,
                                                 bf16_t* __restrict__ ko) {
  __shared__ __align__(16) bf16_t As[128 * 32];
  __shared__ __align__(16) bf16_t Bs[128 * 32];
  const int tid = threadIdx.x, wave = tid >> 6, lane = tid & 63;
  const int m0 = blockIdx.y * 128;
  const bf16_t* Ag0 = A + (size_t)(m0 + wave * 32 + (lane >> 2)) * DIMK + (lane & 3) * 8;
  const bf16_t* Bg0 = BT + (size_t)(wave * 32 + (lane >> 2)) * DIMK + (lane & 3) * 8;
  f32x4 acc[4][4];
#pragma unroll
  for (int m = 0; m < 4; m++)
#pragma unroll
    for (int n = 0; n < 4; n++) acc[m][n] = (f32x4){0.f, 0.f, 0.f, 0.f};
  gemm_core_std(Ag0, DIMK, Bg0, DIMK, DIMK, As, Bs, acc);

  const int row0 = m0 + (wave >> 1) * 64;
  const int col0 = (wave & 1) * 64;
#pragma unroll
  for (int m = 0; m < 4; m++) {
#pragma unroll
    for (int n = 0; n < 4; n++) {
      int col = col0 + n * 16 + (lane & 15);
      float bv = bias[col];
      float g0 = osg[col], b0 = osb[col];
      float g1 = osg[QKD + col], b1 = osb[QKD + col];
      int row = row0 + m * 16 + ((lane >> 4) << 2);
#pragma unroll
      for (int r = 0; r < 4; r++) {
        float sv = silu_f(acc[m][n][r] + bv);
        qo[(size_t)(row + r) * QKD + col] = (bf16_t)(sv * g0 + b0);
        ko[(size_t)(row + r) * QKD + col] = (bf16_t)(sv * g1 + b1);
      }
    }
  }
}

// ---------------------------------------------------------------------------
// Pass A: P tile (ib,jb) = relu( (q@k^T)/(i+1) )^2, causal-masked, bf16,
// packed-triangular storage: tile index = bb*528 + ib*(ib+1)/2 + jb
// ---------------------------------------------------------------------------
__global__ __launch_bounds__(256) void k_qkt(const bf16_t* __restrict__ qb,
                                             const bf16_t* __restrict__ kb,
                                             bf16_t* __restrict__ Pb) {
  const int jb = blockIdx.x, ib = blockIdx.y, bb = blockIdx.z;
  if (jb > ib) return;
  __shared__ __align__(16) bf16_t As[128 * 32];
  __shared__ __align__(16) bf16_t Bs[128 * 32];
  const int tid = threadIdx.x, wave = tid >> 6, lane = tid & 63;
  const bf16_t* Ag0 = qb + (size_t)(bb * SEQ + ib * 128 + wave * 32 + (lane >> 2)) * QKD + (lane & 3) * 8;
  const bf16_t* Bg0 = kb + (size_t)(bb * SEQ + jb * 128 + wave * 32 + (lane >> 2)) * QKD + (lane & 3) * 8;
  f32x4 acc[4][4];
#pragma unroll
  for (int m = 0; m < 4; m++)
#pragma unroll
    for (int n = 0; n < 4; n++) acc[m][n] = (f32x4){0.f, 0.f, 0.f, 0.f};
  gemm_core_std(Ag0, QKD, Bg0, QKD, QKD, As, Bs, acc);

  size_t tb = ((size_t)bb * NTILES + (size_t)ib * (ib + 1) / 2 + jb) * 16384;
  const int il0 = (wave >> 1) * 64, jl0 = (wave & 1) * 64;
#pragma unroll
  for (int m = 0; m < 4; m++) {
#pragma unroll
    for (int n = 0; n < 4; n++) {
      int jloc = jl0 + n * 16 + (lane & 15);
      int jg = jb * 128 + jloc;
#pragma unroll
      for (int r = 0; r < 4; r++) {
        int iloc = il0 + m * 16 + ((lane >> 4) << 2) + r;
        int ig = ib * 128 + iloc;
        float sv = acc[m][n][r] / (float)(ig + 1);
        sv = fmaxf(sv, 0.f);
        sv *= sv;
        if (jg > ig) sv = 0.f;
        Pb[tb + (size_t)iloc * 128 + jloc] = (bf16_t)sv;
      }
    }
  }
}

// ---------------------------------------------------------------------------
// Pass B: out = P @ v (variable causal K), epilogue: *= gate, in place.
// 1D grid, HEAVY-FIRST: w=blockIdx.x decodes ib = 31 - (w>>6) so the longest
// blocks (K=(ib+1)*128) dispatch first; hb/bb fastest so same-ib blocks
// interleave across XCDs. Kills the low-occupancy tail (was: ib ascending,
// heavy blocks last -> Occupancy 18%, MfmaUtil 21%).
// ---------------------------------------------------------------------------
__global__ __launch_bounds__(256) void k_pv(const bf16_t* __restrict__ Pb,
                                            const bf16_t* __restrict__ vT,
                                            bf16_t* __restrict__ gate) {
  const int w = blockIdx.x;
  const int ib = 31 - (w >> 6);
  const int bb = (w >> 4) & 3;
  const int hb = w & 15;
  const int K = (ib + 1) * 128;
  __shared__ __align__(16) bf16_t As[128 * 32];
  __shared__ __align__(16) bf16_t Bs[128 * 32];
  const int tid = threadIdx.x, wave = tid >> 6, lane = tid & 63;
  bf16_t* asw = As + wave * 32 * 32;
  bf16_t* bsw = Bs + wave * 32 * 32;
  const size_t tb = ((size_t)bb * NTILES + (size_t)ib * (ib + 1) / 2) * 16384;
  const int arow = wave * 32 + (lane >> 2);
  const bf16_t* Bg0 = vT + (size_t)(hb * 128 + wave * 32 + (lane >> 2)) * TOKS + bb * SEQ + (lane & 3) * 8;
  const int ar = ((wave >> 1) * 64 + (lane & 15)) * 32 + (lane >> 4) * 8;
  const int br = ((wave & 1) * 64 + (lane & 15)) * 32 + (lane >> 4) * 8;
  f32x4 acc[4][4];
#pragma unroll
  for (int m = 0; m < 4; m++)
#pragma unroll
    for (int n = 0; n < 4; n++) acc[m][n] = (f32x4){0.f, 0.f, 0.f, 0.f};

  for (int k0 = 0; k0 < K; k0 += 32) {
    __syncthreads();
    const bf16_t* At = Pb + tb + (size_t)(k0 >> 7) * 16384 + (k0 & 127) + (lane & 3) * 8;
    gload_lds16(At + arow * 128, asw);
    gload_lds16(At + (arow + 16) * 128, asw + 16 * 32);
    gload_lds16(Bg0 + k0, bsw);
    gload_lds16(Bg0 + k0 + 16 * TOKS, bsw + 16 * 32);
    __syncthreads();
    bf16x8 af[4], bfr[4];
#pragma unroll
    for (int m = 0; m < 4; m++) af[m] = *(const bf16x8*)(As + ar + m * 16 * 32);
#pragma unroll
    for (int n = 0; n < 4; n++) bfr[n] = *(const bf16x8*)(Bs + br + n * 16 * 32);
#pragma unroll
    for (int m = 0; m < 4; m++)
#pragma unroll
      for (int n = 0; n < 4; n++) acc[m][n] = MFMA16(af[m], bfr[n], acc[m][n]);
  }

  const int row0 = ib * 128 + (wave >> 1) * 64;
  const int col0 = hb * 128 + (wave & 1) * 64;
#pragma unroll
  for (int m = 0; m < 4; m++) {
#pragma unroll
    for (int n = 0; n < 4; n++) {
      int col = col0 + n * 16 + (lane & 15);
      int row = row0 + m * 16 + ((lane >> 4) << 2);
#pragma unroll
      for (int r = 0; r < 4; r++) {
        size_t gi = (size_t)(bb * SEQ + row + r) * HID + col;
        float gv = (float)gate[gi];
        gate[gi] = (bf16_t)(acc[m][n][r] * gv);
      }
    }
  }
}

// ---------------------------------------------------------------------------
// Final GEMM: out = gated @ Wo + bo + x   (fp32 out, fp32 residual)
// ---------------------------------------------------------------------------
__global__ __launch_bounds__(256) void k_gemm_out(const bf16_t* __restrict__ A,
                                                  const bf16_t* __restrict__ BT,
                                                  const float* __restrict__ bo,
                                                  const float* __restrict__ x,
                                                  float* __restrict__ out) {
  __shared__ __align__(16) bf16_t As[128 * 32];
  __shared__ __align__(16) bf16_t Bs[128 * 32];
  const int tid = threadIdx.x, wave = tid >> 6, lane = tid & 63;
  const int m0 = blockIdx.y * 128, n0 = blockIdx.x * 128;
  const bf16_t* Ag0 = A + (size_t)(m0 + wave * 32 + (lane >> 2)) * HID + (lane & 3) * 8;
  const bf16_t* Bg0 = BT + (size_t)(n0 + wave * 32 + (lane >> 2)) * HID + (lane & 3) * 8;
  f32x4 acc[4][4];
#pragma unroll
  for (int m = 0; m < 4; m++)
#pragma unroll
    for (int n = 0; n < 4; n++) acc[m][n] = (f32x4){0.f, 0.f, 0.f, 0.f};
  gemm_core_std(Ag0, HID, Bg0, HID, HID, As, Bs, acc);

  const int row0 = m0 + (wave >> 1) * 64;
  const int col0 = n0 + (wave & 1) * 64;
#pragma unroll
  for (int m = 0; m < 4; m++) {
#pragma unroll
    for (int n = 0; n < 4; n++) {
      int col = col0 + n * 16 + (lane & 15);
      float bv = bo[col];
      int row = row0 + m * 16 + ((lane >> 4) << 2);
#pragma unroll
      for (int r = 0; r < 4; r++) {
        size_t gi = (size_t)(row + r) * DIMK + col;
        out[gi] = acc[m][n][r] + bv + x[gi];
      }
    }
  }
}

// ---------------------------------------------------------------------------
extern "C" void kernel_launch(void* const* d_in, const int* in_sizes, int n_in,
                              void* d_out, int out_size, void* d_ws, size_t ws_size,
                              hipStream_t stream) {
  (void)in_sizes; (void)n_in; (void)out_size; (void)ws_size;
  const float* x    = (const float*)d_in[0];
  const float* ln_g = (const float*)d_in[1];
  const float* ln_b = (const float*)d_in[2];
  const float* Wh   = (const float*)d_in[3];
  const float* bh   = (const float*)d_in[4];
  const float* Wqk  = (const float*)d_in[5];
  const float* bqk  = (const float*)d_in[6];
  const float* osg  = (const float*)d_in[7];
  const float* osb  = (const float*)d_in[8];
  const float* Wo   = (const float*)d_in[9];
  const float* bo   = (const float*)d_in[10];
  float* out = (float*)d_out;

  char* ws = (char*)d_ws;
  bf16_t* normed = (bf16_t*)ws;  ws += (size_t)TOKS * DIMK * 2;   // 32 MB
  bf16_t* WhT    = (bf16_t*)ws;  ws += (size_t)H2 * DIMK * 2;     // 8 MB
  bf16_t* WqkT   = (bf16_t*)ws;  ws += (size_t)QKD * DIMK * 2;    // 0.25 MB
  bf16_t* WoT    = (bf16_t*)ws;  ws += (size_t)DIMK * HID * 2;    // 4 MB
  bf16_t* gate   = (bf16_t*)ws;  ws += (size_t)TOKS * HID * 2;    // 64 MB (becomes gated)
  bf16_t* vT     = (bf16_t*)ws;  ws += (size_t)HID * TOKS * 2;    // 64 MB
  bf16_t* qb     = (bf16_t*)ws;  ws += (size_t)TOKS * QKD * 2;    // 4 MB
  bf16_t* kb     = (bf16_t*)ws;  ws += (size_t)TOKS * QKD * 2;    // 4 MB
  bf16_t* Pb     = (bf16_t*)ws;  ws += (size_t)4 * NTILES * 16384 * 2;  // 66 MB

  k_transpose_bf16<<<dim3(H2 / 32, DIMK / 32), 256, 0, stream>>>(Wh, WhT, DIMK, H2);
  k_transpose_bf16<<<dim3(QKD / 32, DIMK / 32), 256, 0, stream>>>(Wqk, WqkT, DIMK, QKD);
  k_transpose_bf16<<<dim3(DIMK / 32, HID / 32), 256, 0, stream>>>(Wo, WoT, HID, DIMK);
  k_layernorm<<<TOKS, 256, 0, stream>>>(x, ln_g, ln_b, normed);
  k_gemm_hidden<<<dim3(H2 / 128, TOKS / 128), 256, 0, stream>>>(normed, WhT, bh, vT, gate);
  k_gemm_qk<<<dim3(1, TOKS / 128), 256, 0, stream>>>(normed, WqkT, bqk, osg, osb, qb, kb);
  k_qkt<<<dim3(SEQ / 128, SEQ / 128, 4), 256, 0, stream>>>(qb, kb, Pb);
  k_pv<<<dim3(16 * 32 * 4), 256, 0, stream>>>(Pb, vT, gate);
  k_gemm_out<<<dim3(DIMK / 128, TOKS / 128), 256, 0, stream>>>(gate, WoT, bo, x, out);
}

// Round 3
// 566.790 us; speedup vs baseline: 1.2012x; 1.0393x over previous
//
#include <hip/hip_runtime.h>
#include <hip/hip_bf16.h>
#include <stdint.h>

typedef __bf16 bf16_t;
typedef __bf16 bf16x4 __attribute__((ext_vector_type(4)));
typedef __bf16 bf16x8 __attribute__((ext_vector_type(8)));
typedef float  f32x4  __attribute__((ext_vector_type(4)));

#define MFMA16(a, b, c) __builtin_amdgcn_mfma_f32_16x16x32_bf16((a), (b), (c), 0, 0, 0)

static constexpr int TOKS   = 16384;  // B*N
static constexpr int SEQ    = 4096;
static constexpr int DIMK   = 1024;
static constexpr int H2     = 4096;   // 2*HIDDEN
static constexpr int HID    = 2048;
static constexpr int QKD    = 128;
static constexpr int NTILES = 528;    // causal 128x128 tiles per batch: 32*33/2
static constexpr int SMEM256 = 3 * (256 * 64 + 128 * 64) * 2;  // 147456 B

// async global->LDS, 16B per lane; LDS dest is wave-uniform base + lane*16 (HW)
__device__ __forceinline__ void gload_lds16(const bf16_t* g, bf16_t* l) {
  __builtin_amdgcn_global_load_lds((__attribute__((address_space(1))) void*)(g),
                                   (__attribute__((address_space(3))) void*)(l),
                                   16, 0, 0);
}

__device__ __forceinline__ float silu_f(float v) { return v / (1.0f + __expf(-v)); }

// ---------------------------------------------------------------------------
// Weight transpose + f32->bf16:  W[K][N] f32  ->  WT[N][K] bf16
// ---------------------------------------------------------------------------
__global__ __launch_bounds__(256) void k_transpose_bf16(const float* __restrict__ W,
                                                        bf16_t* __restrict__ WT,
                                                        int K, int N) {
  __shared__ float t[32][33];
  int n0 = blockIdx.x * 32, k0 = blockIdx.y * 32;
  int tx = threadIdx.x & 31, ty = threadIdx.x >> 5;  // 32 x 8
#pragma unroll
  for (int r = 0; r < 32; r += 8)
    t[ty + r][tx] = W[(size_t)(k0 + ty + r) * N + n0 + tx];
  __syncthreads();
#pragma unroll
  for (int r = 0; r < 32; r += 8)
    WT[(size_t)(n0 + ty + r) * K + k0 + tx] = (bf16_t)t[tx][ty + r];
}

// ---------------------------------------------------------------------------
// LayerNorm: x[16384][1024] f32 -> normed bf16
// ---------------------------------------------------------------------------
__global__ __launch_bounds__(256) void k_layernorm(const float* __restrict__ x,
                                                   const float* __restrict__ g,
                                                   const float* __restrict__ b,
                                                   bf16_t* __restrict__ out) {
  int row = blockIdx.x, t = threadIdx.x;
  const float4* xr = (const float4*)(x + (size_t)row * DIMK);
  float4 v = xr[t];
  float s  = v.x + v.y + v.z + v.w;
  float ss = v.x * v.x + v.y * v.y + v.z * v.z + v.w * v.w;
#pragma unroll
  for (int o = 1; o < 64; o <<= 1) { s += __shfl_xor(s, o); ss += __shfl_xor(ss, o); }
  __shared__ float red[8];
  int wave = t >> 6, lane = t & 63;
  if (lane == 0) { red[wave] = s; red[wave + 4] = ss; }
  __syncthreads();
  s  = red[0] + red[1] + red[2] + red[3];
  ss = red[4] + red[5] + red[6] + red[7];
  float mean = s * (1.0f / DIMK);
  float var  = ss * (1.0f / DIMK) - mean * mean;
  float rstd = rsqrtf(var + 1e-5f);
  float4 gg = ((const float4*)g)[t];
  float4 bb = ((const float4*)b)[t];
  bf16x4 o4;
  o4[0] = (bf16_t)((v.x - mean) * rstd * gg.x + bb.x);
  o4[1] = (bf16_t)((v.y - mean) * rstd * gg.y + bb.y);
  o4[2] = (bf16_t)((v.z - mean) * rstd * gg.z + bb.z);
  o4[3] = (bf16_t)((v.w - mean) * rstd * gg.w + bb.w);
  *(bf16x4*)(out + (size_t)row * DIMK + t * 4) = o4;
}

// ---------------------------------------------------------------------------
// 256x128 deep-pipelined GEMM core. 512 threads / 8 waves (4M x 2N), BK=64.
// Triple-buffered LDS (A 32KB + B 16KB per buf, x3 = 144KB dynamic).
// Per K-tile kt: vmcnt(6) [kt drained, kt+1's 6 loads in flight] -> s_barrier
// -> stage kt+2 into buf[(kt+2)%3] (provably dead: all waves finished reading
// it as kt-1 before this barrier) -> 16 swizzled ds_read_b128 + 32 MFMA.
// LDS swizzle: element col ^= (row&7)<<3 (read side); inverse pre-swizzle on
// the per-lane GLOBAL source address (linear LDS dest, rule m104/m173).
// ---------------------------------------------------------------------------
__device__ __forceinline__ void core256(const bf16_t* __restrict__ A, int lda,
                                        const bf16_t* __restrict__ BT, int ldb,
                                        int m0, int n0, int K,
                                        bf16_t* Abuf, bf16_t* Bbuf,
                                        f32x4 acc[4][4]) {
  const int tid = threadIdx.x, wid = tid >> 6, lane = tid & 63;
  const int wm = wid >> 1, wn = wid & 1;
  const int NK = K >> 6;
  const bf16_t* Ag = A + (size_t)m0 * lda;
  const bf16_t* Bg = BT + (size_t)n0 * ldb;
  const int lr = lane >> 3;          // row within 8-row chunk
  const int lc = (lane & 7) * 8;     // col element base

  auto stage = [&](int kt, int buf) {
    const bf16_t* Ak = Ag + kt * 64;
    const bf16_t* Bk = Bg + kt * 64;
    bf16_t* Al = Abuf + buf * 16384;
    bf16_t* Bl = Bbuf + buf * 8192;
#pragma unroll
    for (int c = 0; c < 4; ++c) {
      int row = wid * 32 + c * 8 + lr;
      int col = lc ^ ((row & 7) << 3);
      gload_lds16(Ak + (size_t)row * lda + col, Al + (wid * 4 + c) * 512);
    }
#pragma unroll
    for (int c = 0; c < 2; ++c) {
      int row = wid * 16 + c * 8 + lr;
      int col = lc ^ ((row & 7) << 3);
      gload_lds16(Bk + (size_t)row * ldb + col, Bl + (wid * 2 + c) * 512);
    }
  };

  // fragment LDS element offsets (buf-relative), swizzled
  int aoff[4][2], boff[4][2];
#pragma unroll
  for (int mi = 0; mi < 4; ++mi)
#pragma unroll
    for (int kk = 0; kk < 2; ++kk) {
      int arow = wm * 64 + mi * 16 + (lane & 15);
      int brow = wn * 64 + mi * 16 + (lane & 15);
      int cb = kk * 32 + (lane >> 4) * 8;
      aoff[mi][kk] = arow * 64 + (cb ^ ((arow & 7) << 3));
      boff[mi][kk] = brow * 64 + (cb ^ ((brow & 7) << 3));
    }

  stage(0, 0);
  stage(1, 1);
  for (int kt = 0; kt < NK; ++kt) {
    if (kt + 1 < NK) { asm volatile("s_waitcnt vmcnt(6)" ::: "memory"); }
    else             { asm volatile("s_waitcnt vmcnt(0)" ::: "memory"); }
    __builtin_amdgcn_sched_barrier(0);
    __builtin_amdgcn_s_barrier();
    __builtin_amdgcn_sched_barrier(0);
    if (kt + 2 < NK) stage(kt + 2, (kt + 2) % 3);
    int buf = kt % 3;
    bf16_t* Al = Abuf + buf * 16384;
    bf16_t* Bl = Bbuf + buf * 8192;
    bf16x8 af[4][2], bfr[4][2];
#pragma unroll
    for (int mi = 0; mi < 4; ++mi)
#pragma unroll
      for (int kk = 0; kk < 2; ++kk) {
        af[mi][kk]  = *(const bf16x8*)(Al + aoff[mi][kk]);
        bfr[mi][kk] = *(const bf16x8*)(Bl + boff[mi][kk]);
      }
    __builtin_amdgcn_s_setprio(1);
#pragma unroll
    for (int kk = 0; kk < 2; ++kk)
#pragma unroll
      for (int mi = 0; mi < 4; ++mi)
#pragma unroll
        for (int nj = 0; nj < 4; ++nj)
          acc[mi][nj] = MFMA16(af[mi][kk], bfr[nj][kk], acc[mi][nj]);
    __builtin_amdgcn_s_setprio(0);
  }
}

// GEMM1 on 256-core: silu(normed @ Wh + bh) -> vT (transposed) / gate
__global__ __launch_bounds__(512) void k_gemm_hidden256(const bf16_t* __restrict__ A,
                                                        const bf16_t* __restrict__ BT,
                                                        const float* __restrict__ bias,
                                                        bf16_t* __restrict__ vT,
                                                        bf16_t* __restrict__ gate) {
  extern __shared__ __align__(16) char lds[];
  bf16_t* Abuf = (bf16_t*)lds;
  bf16_t* Bbuf = (bf16_t*)(lds + 3 * 16384 * 2);
  const int nwg = gridDim.x;
  const int bid = blockIdx.x;
  const int swz = (bid & 7) * (nwg >> 3) + (bid >> 3);   // XCD-contiguous
  const int mblk = swz >> 5, nblk = swz & 31;            // nb = H2/128 = 32
  const int m0 = mblk * 256, n0 = nblk * 128;
  f32x4 acc[4][4];
#pragma unroll
  for (int i = 0; i < 4; ++i)
#pragma unroll
    for (int j = 0; j < 4; ++j) acc[i][j] = (f32x4){0.f, 0.f, 0.f, 0.f};
  core256(A, DIMK, BT, DIMK, m0, n0, DIMK, Abuf, Bbuf, acc);

  const int tid = threadIdx.x, wid = tid >> 6, lane = tid & 63;
  const int wm = wid >> 1, wn = wid & 1;
  const int row0 = m0 + wm * 64, col0 = n0 + wn * 64;
#pragma unroll
  for (int mi = 0; mi < 4; ++mi)
#pragma unroll
    for (int nj = 0; nj < 4; ++nj) {
      int col = col0 + nj * 16 + (lane & 15);
      float bv = bias[col];
      int row = row0 + mi * 16 + ((lane >> 4) << 2);
      float sv[4];
#pragma unroll
      for (int r = 0; r < 4; ++r) sv[r] = silu_f(acc[mi][nj][r] + bv);
      if (col < HID) {
        bf16x4 pk;
#pragma unroll
        for (int r = 0; r < 4; ++r) pk[r] = (bf16_t)sv[r];
        *(bf16x4*)(vT + (size_t)col * TOKS + row) = pk;
      } else {
#pragma unroll
        for (int r = 0; r < 4; ++r)
          gate[(size_t)(row + r) * HID + (col - HID)] = (bf16_t)sv[r];
      }
    }
}

// Final GEMM on 256-core: out = gated @ Wo + bo + x (fp32 out + residual)
__global__ __launch_bounds__(512) void k_gemm_out256(const bf16_t* __restrict__ A,
                                                     const bf16_t* __restrict__ BT,
                                                     const float* __restrict__ bo,
                                                     const float* __restrict__ x,
                                                     float* __restrict__ out) {
  extern __shared__ __align__(16) char lds[];
  bf16_t* Abuf = (bf16_t*)lds;
  bf16_t* Bbuf = (bf16_t*)(lds + 3 * 16384 * 2);
  const int nwg = gridDim.x;
  const int bid = blockIdx.x;
  const int swz = (bid & 7) * (nwg >> 3) + (bid >> 3);
  const int mblk = swz >> 3, nblk = swz & 7;             // nb = DIMK/128 = 8
  const int m0 = mblk * 256, n0 = nblk * 128;
  f32x4 acc[4][4];
#pragma unroll
  for (int i = 0; i < 4; ++i)
#pragma unroll
    for (int j = 0; j < 4; ++j) acc[i][j] = (f32x4){0.f, 0.f, 0.f, 0.f};
  core256(A, HID, BT, HID, m0, n0, HID, Abuf, Bbuf, acc);

  const int tid = threadIdx.x, wid = tid >> 6, lane = tid & 63;
  const int wm = wid >> 1, wn = wid & 1;
  const int row0 = m0 + wm * 64, col0 = n0 + wn * 64;
#pragma unroll
  for (int mi = 0; mi < 4; ++mi)
#pragma unroll
    for (int nj = 0; nj < 4; ++nj) {
      int col = col0 + nj * 16 + (lane & 15);
      float bv = bo[col];
      int row = row0 + mi * 16 + ((lane >> 4) << 2);
#pragma unroll
      for (int r = 0; r < 4; ++r) {
        size_t gi = (size_t)(row + r) * DIMK + col;
        out[gi] = acc[mi][nj][r] + bv + x[gi];
      }
    }
}

// ---------------------------------------------------------------------------
// 128x128 m97-style core (kept for qk / qkt / pv)
// ---------------------------------------------------------------------------
__device__ __forceinline__ void gemm_core_std(const bf16_t* __restrict__ Ag0, int lda,
                                              const bf16_t* __restrict__ Bg0, int ldb,
                                              int K, bf16_t* As, bf16_t* Bs,
                                              f32x4 acc[4][4]) {
  const int tid = threadIdx.x;
  const int wave = tid >> 6, lane = tid & 63;
  bf16_t* asw = As + wave * 32 * 32;
  bf16_t* bsw = Bs + wave * 32 * 32;
  const int ar = ((wave >> 1) * 64 + (lane & 15)) * 32 + (lane >> 4) * 8;
  const int br = ((wave & 1) * 64 + (lane & 15)) * 32 + (lane >> 4) * 8;
  for (int k0 = 0; k0 < K; k0 += 32) {
    __syncthreads();
    gload_lds16(Ag0 + k0, asw);
    gload_lds16(Ag0 + k0 + 16 * lda, asw + 16 * 32);
    gload_lds16(Bg0 + k0, bsw);
    gload_lds16(Bg0 + k0 + 16 * ldb, bsw + 16 * 32);
    __syncthreads();
    bf16x8 af[4], bfr[4];
#pragma unroll
    for (int m = 0; m < 4; m++) af[m] = *(const bf16x8*)(As + ar + m * 16 * 32);
#pragma unroll
    for (int n = 0; n < 4; n++) bfr[n] = *(const bf16x8*)(Bs + br + n * 16 * 32);
#pragma unroll
    for (int m = 0; m < 4; m++)
#pragma unroll
      for (int n = 0; n < 4; n++) acc[m][n] = MFMA16(af[m], bfr[n], acc[m][n]);
  }
}

// qk GEMM: qkv = silu(normed @ Wqk + bqk); q/k = qkv*gamma+beta (bf16)
__global__ __launch_bounds__(256) void k_gemm_qk(const bf16_t* __restrict__ A,
                                                 const bf16_t* __restrict__ BT,
                                                 const float* __restrict__ bias,
                                                 const float* __restrict__ osg,
                                                 const float* __restrict__ osb,
                                                 bf16_t* __restrict__ qo,
                                                 bf16_t* __restrict__ ko) {
  __shared__ __align__(16) bf16_t As[128 * 32];
  __shared__ __align__(16) bf16_t Bs[128 * 32];
  const int tid = threadIdx.x, wave = tid >> 6, lane = tid & 63;
  const int m0 = blockIdx.y * 128;
  const bf16_t* Ag0 = A + (size_t)(m0 + wave * 32 + (lane >> 2)) * DIMK + (lane & 3) * 8;
  const bf16_t* Bg0 = BT + (size_t)(wave * 32 + (lane >> 2)) * DIMK + (lane & 3) * 8;
  f32x4 acc[4][4];
#pragma unroll
  for (int m = 0; m < 4; m++)
#pragma unroll
    for (int n = 0; n < 4; n++) acc[m][n] = (f32x4){0.f, 0.f, 0.f, 0.f};
  gemm_core_std(Ag0, DIMK, Bg0, DIMK, DIMK, As, Bs, acc);

  const int row0 = m0 + (wave >> 1) * 64;
  const int col0 = (wave & 1) * 64;
#pragma unroll
  for (int m = 0; m < 4; m++) {
#pragma unroll
    for (int n = 0; n < 4; n++) {
      int col = col0 + n * 16 + (lane & 15);
      float bv = bias[col];
      float g0 = osg[col], b0 = osb[col];
      float g1 = osg[QKD + col], b1 = osb[QKD + col];
      int row = row0 + m * 16 + ((lane >> 4) << 2);
#pragma unroll
      for (int r = 0; r < 4; r++) {
        float sv = silu_f(acc[m][n][r] + bv);
        qo[(size_t)(row + r) * QKD + col] = (bf16_t)(sv * g0 + b0);
        ko[(size_t)(row + r) * QKD + col] = (bf16_t)(sv * g1 + b1);
      }
    }
  }
}

// Pass A: P tile (ib,jb) = relu( (q@k^T)/(i+1) )^2, causal, packed-triangular
__global__ __launch_bounds__(256) void k_qkt(const bf16_t* __restrict__ qb,
                                             const bf16_t* __restrict__ kb,
                                             bf16_t* __restrict__ Pb) {
  const int jb = blockIdx.x, ib = blockIdx.y, bb = blockIdx.z;
  if (jb > ib) return;
  __shared__ __align__(16) bf16_t As[128 * 32];
  __shared__ __align__(16) bf16_t Bs[128 * 32];
  const int tid = threadIdx.x, wave = tid >> 6, lane = tid & 63;
  const bf16_t* Ag0 = qb + (size_t)(bb * SEQ + ib * 128 + wave * 32 + (lane >> 2)) * QKD + (lane & 3) * 8;
  const bf16_t* Bg0 = kb + (size_t)(bb * SEQ + jb * 128 + wave * 32 + (lane >> 2)) * QKD + (lane & 3) * 8;
  f32x4 acc[4][4];
#pragma unroll
  for (int m = 0; m < 4; m++)
#pragma unroll
    for (int n = 0; n < 4; n++) acc[m][n] = (f32x4){0.f, 0.f, 0.f, 0.f};
  gemm_core_std(Ag0, QKD, Bg0, QKD, QKD, As, Bs, acc);

  size_t tb = ((size_t)bb * NTILES + (size_t)ib * (ib + 1) / 2 + jb) * 16384;
  const int il0 = (wave >> 1) * 64, jl0 = (wave & 1) * 64;
#pragma unroll
  for (int m = 0; m < 4; m++) {
#pragma unroll
    for (int n = 0; n < 4; n++) {
      int jloc = jl0 + n * 16 + (lane & 15);
      int jg = jb * 128 + jloc;
#pragma unroll
      for (int r = 0; r < 4; r++) {
        int iloc = il0 + m * 16 + ((lane >> 4) << 2) + r;
        int ig = ib * 128 + iloc;
        float sv = acc[m][n][r] / (float)(ig + 1);
        sv = fmaxf(sv, 0.f);
        sv *= sv;
        if (jg > ig) sv = 0.f;
        Pb[tb + (size_t)iloc * 128 + jloc] = (bf16_t)sv;
      }
    }
  }
}

// Pass B: out = P @ v (variable causal K), *= gate in place; heavy-first 1D grid
__global__ __launch_bounds__(256) void k_pv(const bf16_t* __restrict__ Pb,
                                            const bf16_t* __restrict__ vT,
                                            bf16_t* __restrict__ gate) {
  const int w = blockIdx.x;
  const int ib = 31 - (w >> 6);
  const int bb = (w >> 4) & 3;
  const int hb = w & 15;
  const int K = (ib + 1) * 128;
  __shared__ __align__(16) bf16_t As[128 * 32];
  __shared__ __align__(16) bf16_t Bs[128 * 32];
  const int tid = threadIdx.x, wave = tid >> 6, lane = tid & 63;
  bf16_t* asw = As + wave * 32 * 32;
  bf16_t* bsw = Bs + wave * 32 * 32;
  const size_t tb = ((size_t)bb * NTILES + (size_t)ib * (ib + 1) / 2) * 16384;
  const int arow = wave * 32 + (lane >> 2);
  const bf16_t* Bg0 = vT + (size_t)(hb * 128 + wave * 32 + (lane >> 2)) * TOKS + bb * SEQ + (lane & 3) * 8;
  const int ar = ((wave >> 1) * 64 + (lane & 15)) * 32 + (lane >> 4) * 8;
  const int br = ((wave & 1) * 64 + (lane & 15)) * 32 + (lane >> 4) * 8;
  f32x4 acc[4][4];
#pragma unroll
  for (int m = 0; m < 4; m++)
#pragma unroll
    for (int n = 0; n < 4; n++) acc[m][n] = (f32x4){0.f, 0.f, 0.f, 0.f};

  for (int k0 = 0; k0 < K; k0 += 32) {
    __syncthreads();
    const bf16_t* At = Pb + tb + (size_t)(k0 >> 7) * 16384 + (k0 & 127) + (lane & 3) * 8;
    gload_lds16(At + arow * 128, asw);
    gload_lds16(At + (arow + 16) * 128, asw + 16 * 32);
    gload_lds16(Bg0 + k0, bsw);
    gload_lds16(Bg0 + k0 + 16 * TOKS, bsw + 16 * 32);
    __syncthreads();
    bf16x8 af[4], bfr[4];
#pragma unroll
    for (int m = 0; m < 4; m++) af[m] = *(const bf16x8*)(As + ar + m * 16 * 32);
#pragma unroll
    for (int n = 0; n < 4; n++) bfr[n] = *(const bf16x8*)(Bs + br + n * 16 * 32);
#pragma unroll
    for (int m = 0; m < 4; m++)
#pragma unroll
      for (int n = 0; n < 4; n++) acc[m][n] = MFMA16(af[m], bfr[n], acc[m][n]);
  }

  const int row0 = ib * 128 + (wave >> 1) * 64;
  const int col0 = hb * 128 + (wave & 1) * 64;
#pragma unroll
  for (int m = 0; m < 4; m++) {
#pragma unroll
    for (int n = 0; n < 4; n++) {
      int col = col0 + n * 16 + (lane & 15);
      int row = row0 + m * 16 + ((lane >> 4) << 2);
#pragma unroll
      for (int r = 0; r < 4; r++) {
        size_t gi = (size_t)(bb * SEQ + row + r) * HID + col;
        float gv = (float)gate[gi];
        gate[gi] = (bf16_t)(acc[m][n][r] * gv);
      }
    }
  }
}

// ---------------------------------------------------------------------------
extern "C" void kernel_launch(void* const* d_in, const int* in_sizes, int n_in,
                              void* d_out, int out_size, void* d_ws, size_t ws_size,
                              hipStream_t stream) {
  (void)in_sizes; (void)n_in; (void)out_size; (void)ws_size;
  const float* x    = (const float*)d_in[0];
  const float* ln_g = (const float*)d_in[1];
  const float* ln_b = (const float*)d_in[2];
  const float* Wh   = (const float*)d_in[3];
  const float* bh   = (const float*)d_in[4];
  const float* Wqk  = (const float*)d_in[5];
  const float* bqk  = (const float*)d_in[6];
  const float* osg  = (const float*)d_in[7];
  const float* osb  = (const float*)d_in[8];
  const float* Wo   = (const float*)d_in[9];
  const float* bo   = (const float*)d_in[10];
  float* out = (float*)d_out;

  char* ws = (char*)d_ws;
  bf16_t* normed = (bf16_t*)ws;  ws += (size_t)TOKS * DIMK * 2;   // 32 MB
  bf16_t* WhT    = (bf16_t*)ws;  ws += (size_t)H2 * DIMK * 2;     // 8 MB
  bf16_t* WqkT   = (bf16_t*)ws;  ws += (size_t)QKD * DIMK * 2;    // 0.25 MB
  bf16_t* WoT    = (bf16_t*)ws;  ws += (size_t)DIMK * HID * 2;    // 4 MB
  bf16_t* gate   = (bf16_t*)ws;  ws += (size_t)TOKS * HID * 2;    // 64 MB (becomes gated)
  bf16_t* vT     = (bf16_t*)ws;  ws += (size_t)HID * TOKS * 2;    // 64 MB
  bf16_t* qb     = (bf16_t*)ws;  ws += (size_t)TOKS * QKD * 2;    // 4 MB
  bf16_t* kb     = (bf16_t*)ws;  ws += (size_t)TOKS * QKD * 2;    // 4 MB
  bf16_t* Pb     = (bf16_t*)ws;  ws += (size_t)4 * NTILES * 16384 * 2;  // 66 MB

  hipFuncSetAttribute((const void*)k_gemm_hidden256,
                      hipFuncAttributeMaxDynamicSharedMemorySize, SMEM256);
  hipFuncSetAttribute((const void*)k_gemm_out256,
                      hipFuncAttributeMaxDynamicSharedMemorySize, SMEM256);

  k_transpose_bf16<<<dim3(H2 / 32, DIMK / 32), 256, 0, stream>>>(Wh, WhT, DIMK, H2);
  k_transpose_bf16<<<dim3(QKD / 32, DIMK / 32), 256, 0, stream>>>(Wqk, WqkT, DIMK, QKD);
  k_transpose_bf16<<<dim3(DIMK / 32, HID / 32), 256, 0, stream>>>(Wo, WoT, HID, DIMK);
  k_layernorm<<<TOKS, 256, 0, stream>>>(x, ln_g, ln_b, normed);
  k_gemm_hidden256<<<dim3((TOKS / 256) * (H2 / 128)), 512, SMEM256, stream>>>(normed, WhT, bh, vT, gate);
  k_gemm_qk<<<dim3(1, TOKS / 128), 256, 0, stream>>>(normed, WqkT, bqk, osg, osb, qb, kb);
  k_qkt<<<dim3(SEQ / 128, SEQ / 128, 4), 256, 0, stream>>>(qb, kb, Pb);
  k_pv<<<dim3(16 * 32 * 4), 256, 0, stream>>>(Pb, vT, gate);
  k_gemm_out256<<<dim3((TOKS / 256) * (DIMK / 128)), 512, SMEM256, stream>>>(gate, WoT, bo, x, out);
}

// Round 4
// 537.766 us; speedup vs baseline: 1.2660x; 1.0540x over previous
//
#include <hip/hip_runtime.h>
#include <hip/hip_bf16.h>
#include <stdint.h>

typedef __bf16 bf16_t;
typedef __bf16 bf16x4 __attribute__((ext_vector_type(4)));
typedef __bf16 bf16x8 __attribute__((ext_vector_type(8)));
typedef float  f32x4  __attribute__((ext_vector_type(4)));

#define MFMA16(a, b, c) __builtin_amdgcn_mfma_f32_16x16x32_bf16((a), (b), (c), 0, 0, 0)

static constexpr int TOKS   = 16384;  // B*N
static constexpr int SEQ    = 4096;
static constexpr int DIMK   = 1024;
static constexpr int H2     = 4096;   // 2*HIDDEN
static constexpr int HID    = 2048;
static constexpr int QKD    = 128;
static constexpr int NTILES = 528;    // causal 128x128 tiles per batch: 32*33/2
static constexpr int SMEM8P = 131072; // 2buf x 2half x 128x64 x 2(A,B) x 2B

// async global->LDS, 16B per lane; LDS dest is wave-uniform base + lane*16 (HW)
__device__ __forceinline__ void gload_lds16(const bf16_t* g, bf16_t* l) {
  __builtin_amdgcn_global_load_lds((__attribute__((address_space(1))) void*)(g),
                                   (__attribute__((address_space(3))) void*)(l),
                                   16, 0, 0);
}

__device__ __forceinline__ float silu_f(float v) { return v / (1.0f + __expf(-v)); }

#define BARRIER() do { __builtin_amdgcn_sched_barrier(0); \
                       __builtin_amdgcn_s_barrier();      \
                       __builtin_amdgcn_sched_barrier(0); } while (0)

// ---------------------------------------------------------------------------
// Weight transpose + f32->bf16:  W[K][N] f32  ->  WT[N][K] bf16
// ---------------------------------------------------------------------------
__global__ __launch_bounds__(256) void k_transpose_bf16(const float* __restrict__ W,
                                                        bf16_t* __restrict__ WT,
                                                        int K, int N) {
  __shared__ float t[32][33];
  int n0 = blockIdx.x * 32, k0 = blockIdx.y * 32;
  int tx = threadIdx.x & 31, ty = threadIdx.x >> 5;  // 32 x 8
#pragma unroll
  for (int r = 0; r < 32; r += 8)
    t[ty + r][tx] = W[(size_t)(k0 + ty + r) * N + n0 + tx];
  __syncthreads();
#pragma unroll
  for (int r = 0; r < 32; r += 8)
    WT[(size_t)(n0 + ty + r) * K + k0 + tx] = (bf16_t)t[tx][ty + r];
}

// ---------------------------------------------------------------------------
// LayerNorm: x[16384][1024] f32 -> normed bf16
// ---------------------------------------------------------------------------
__global__ __launch_bounds__(256) void k_layernorm(const float* __restrict__ x,
                                                   const float* __restrict__ g,
                                                   const float* __restrict__ b,
                                                   bf16_t* __restrict__ out) {
  int row = blockIdx.x, t = threadIdx.x;
  const float4* xr = (const float4*)(x + (size_t)row * DIMK);
  float4 v = xr[t];
  float s  = v.x + v.y + v.z + v.w;
  float ss = v.x * v.x + v.y * v.y + v.z * v.z + v.w * v.w;
#pragma unroll
  for (int o = 1; o < 64; o <<= 1) { s += __shfl_xor(s, o); ss += __shfl_xor(ss, o); }
  __shared__ float red[8];
  int wave = t >> 6, lane = t & 63;
  if (lane == 0) { red[wave] = s; red[wave + 4] = ss; }
  __syncthreads();
  s  = red[0] + red[1] + red[2] + red[3];
  ss = red[4] + red[5] + red[6] + red[7];
  float mean = s * (1.0f / DIMK);
  float var  = ss * (1.0f / DIMK) - mean * mean;
  float rstd = rsqrtf(var + 1e-5f);
  float4 gg = ((const float4*)g)[t];
  float4 bb = ((const float4*)b)[t];
  bf16x4 o4;
  o4[0] = (bf16_t)((v.x - mean) * rstd * gg.x + bb.x);
  o4[1] = (bf16_t)((v.y - mean) * rstd * gg.y + bb.y);
  o4[2] = (bf16_t)((v.z - mean) * rstd * gg.z + bb.z);
  o4[3] = (bf16_t)((v.w - mean) * rstd * gg.w + bb.w);
  *(bf16x4*)(out + (size_t)row * DIMK + t * 4) = o4;
}

// ---------------------------------------------------------------------------
// 8-phase 256x256 GEMM core (m201-style). 512 thr / 8 waves (2M x 4N), BK=64.
// LDS: A,B each 2buf x 2half x [128][64] bf16 (32KB+32KB per op => 128KB).
// Read-side XOR swizzle: 16B granule g ^= (row&7); stage pre-swizzles the
// per-lane GLOBAL column so LDS dest stays linear (both-sides rule).
// Per group g (one K-tile, 4 phases):
//  p0: ds_read A[mi0..7]kk0 + B[nj0..3]kk0 (12); stage B(g+1)h0; BAR; 16 MFMA (mh0,kk0); BAR
//  p1: ds_read A kk1 (8);                        stage B(g+1)h1; BAR; 16 MFMA (mh1,kk0); BAR
//  p2: ds_read B kk1 (4);                        stage A(g+2)h0; BAR; 16 MFMA (mh0,kk1); BAR
//  p3:                                           stage A(g+2)h1; BAR; 16 MFMA (mh1,kk1);
//      vmcnt(4) [drains K-tile g+1 exactly; A(g+2) stays in flight]; BAR
// Hazards: stage targets are provably dead (>=1 barrier after their last
// ds_read issue); cross-wave LDS visibility via vmcnt-before-barrier.
// ---------------------------------------------------------------------------
#define MFMAQ(MH, KK)                                                         \
  _Pragma("unroll")                                                           \
  for (int mi = 0; mi < 4; ++mi)                                              \
    _Pragma("unroll")                                                         \
    for (int nj = 0; nj < 4; ++nj)                                            \
      acc[(MH) * 4 + mi][nj] =                                                \
          MFMA16(aF[(MH) * 4 + mi][KK], bF[nj][KK], acc[(MH) * 4 + mi][nj]);

__device__ __forceinline__ void core8p(const bf16_t* __restrict__ Ag, int lda,
                                       const bf16_t* __restrict__ Bg, int ldb,
                                       int NK, bf16_t* AS, bf16_t* BS,
                                       f32x4 (&acc)[8][4]) {
  const int tid = threadIdx.x, wid = tid >> 6, lane = tid & 63;
  const int wm = wid >> 2, wn = wid & 3;
  // staging addressing: chunk (wid*2+c) covers 8 rows of a 128-row half
  const int srow = lane >> 3;                 // row within 8-row chunk
  const int scol = ((lane & 7) ^ srow) * 8;   // pre-swizzled source column

  auto stA = [&](int kt, int h) {
    const bf16_t* s = Ag + (size_t)(h * 128 + wid * 16 + srow) * lda + kt * 64 + scol;
    bf16_t* d = AS + ((kt & 1) * 2 + h) * 8192 + wid * 1024;
    gload_lds16(s, d);
    gload_lds16(s + 8 * lda, d + 512);
  };
  auto stB = [&](int kt, int h) {
    const bf16_t* s = Bg + (size_t)(h * 128 + wid * 16 + srow) * ldb + kt * 64 + scol;
    bf16_t* d = BS + ((kt & 1) * 2 + h) * 8192 + wid * 1024;
    gload_lds16(s, d);
    gload_lds16(s + 8 * ldb, d + 512);
  };

  // fragment read pointers (swizzled): row = frag*16 + (lane&15),
  // granule = (kk*4 + (lane>>4)) ^ (lane&7); row&7 == lane&7 always.
  const int g0 = (lane >> 4) ^ (lane & 7);
  const bf16_t* pA0 = AS + wm * 8192 + (lane & 15) * 64 + g0 * 8;
  const bf16_t* pA1 = AS + wm * 8192 + (lane & 15) * 64 + (g0 ^ 4) * 8;
  const bf16_t* pB0 = BS + (wn >> 1) * 8192 + ((wn & 1) * 64 + (lane & 15)) * 64 + g0 * 8;
  const bf16_t* pB1 = BS + (wn >> 1) * 8192 + ((wn & 1) * 64 + (lane & 15)) * 64 + (g0 ^ 4) * 8;

  bf16x8 aF[8][2], bF[4][2];

  // prologue: kt0 fully + kt1 A-halves (NK >= 2 required)
  stA(0, 0); stA(0, 1); stB(0, 0); stB(0, 1);
  stA(1, 0); stA(1, 1);
  asm volatile("s_waitcnt vmcnt(4)" ::: "memory");
  BARRIER();

  for (int g = 0; g < NK; ++g) {
    const int buf = (g & 1) * 16384;
    // ---- p0
#pragma unroll
    for (int mi = 0; mi < 8; ++mi) aF[mi][0] = *(const bf16x8*)(pA0 + buf + mi * 1024);
#pragma unroll
    for (int nj = 0; nj < 4; ++nj) bF[nj][0] = *(const bf16x8*)(pB0 + buf + nj * 1024);
    if (g + 1 < NK) stB(g + 1, 0);
    BARRIER();
    __builtin_amdgcn_s_setprio(1);
    MFMAQ(0, 0);
    __builtin_amdgcn_s_setprio(0);
    BARRIER();
    // ---- p1
#pragma unroll
    for (int mi = 0; mi < 8; ++mi) aF[mi][1] = *(const bf16x8*)(pA1 + buf + mi * 1024);
    if (g + 1 < NK) stB(g + 1, 1);
    BARRIER();
    __builtin_amdgcn_s_setprio(1);
    MFMAQ(1, 0);
    __builtin_amdgcn_s_setprio(0);
    BARRIER();
    // ---- p2
#pragma unroll
    for (int nj = 0; nj < 4; ++nj) bF[nj][1] = *(const bf16x8*)(pB1 + buf + nj * 1024);
    if (g + 2 < NK) stA(g + 2, 0);
    BARRIER();
    __builtin_amdgcn_s_setprio(1);
    MFMAQ(0, 1);
    __builtin_amdgcn_s_setprio(0);
    BARRIER();
    // ---- p3
    if (g + 2 < NK) stA(g + 2, 1);
    BARRIER();
    __builtin_amdgcn_s_setprio(1);
    MFMAQ(1, 1);
    __builtin_amdgcn_s_setprio(0);
    if (g < NK - 2)       { asm volatile("s_waitcnt vmcnt(4)" ::: "memory"); }
    else if (g == NK - 2) { asm volatile("s_waitcnt vmcnt(0)" ::: "memory"); }
    BARRIER();
  }
}

// GEMM1 on 8-phase core: silu(normed @ Wh + bh) -> vT (transposed) / gate
__global__ __launch_bounds__(512, 2) void k_gemm_hidden8p(const bf16_t* __restrict__ A,
                                                          const bf16_t* __restrict__ BT,
                                                          const float* __restrict__ bias,
                                                          bf16_t* __restrict__ vT,
                                                          bf16_t* __restrict__ gate) {
  extern __shared__ __align__(16) char lds[];
  bf16_t* AS = (bf16_t*)lds;
  bf16_t* BS = AS + 32768;
  const int nwg = gridDim.x, bid = blockIdx.x;
  const int swz = (bid & 7) * (nwg >> 3) + (bid >> 3);   // XCD-contiguous
  const int mblk = swz >> 4, nblk = swz & 15;            // N/256 = 16
  const int m0 = mblk * 256, n0 = nblk * 256;
  f32x4 acc[8][4];
#pragma unroll
  for (int i = 0; i < 8; ++i)
#pragma unroll
    for (int j = 0; j < 4; ++j) acc[i][j] = (f32x4){0.f, 0.f, 0.f, 0.f};
  core8p(A + (size_t)m0 * DIMK, DIMK, BT + (size_t)n0 * DIMK, DIMK,
         DIMK / 64, AS, BS, acc);

  const int tid = threadIdx.x, wid = tid >> 6, lane = tid & 63;
  const int wm = wid >> 2, wn = wid & 3;
  const int row0 = m0 + wm * 128, col0 = n0 + wn * 64;
#pragma unroll
  for (int mi = 0; mi < 8; ++mi)
#pragma unroll
    for (int nj = 0; nj < 4; ++nj) {
      int col = col0 + nj * 16 + (lane & 15);
      float bv = bias[col];
      int row = row0 + mi * 16 + ((lane >> 4) << 2);
      float sv[4];
#pragma unroll
      for (int r = 0; r < 4; ++r) sv[r] = silu_f(acc[mi][nj][r] + bv);
      if (col < HID) {
        bf16x4 pk;
#pragma unroll
        for (int r = 0; r < 4; ++r) pk[r] = (bf16_t)sv[r];
        *(bf16x4*)(vT + (size_t)col * TOKS + row) = pk;
      } else {
#pragma unroll
        for (int r = 0; r < 4; ++r)
          gate[(size_t)(row + r) * HID + (col - HID)] = (bf16_t)sv[r];
      }
    }
}

// Final GEMM on 8-phase core: out = gated @ Wo + bo + x (fp32 out + residual)
__global__ __launch_bounds__(512, 2) void k_gemm_out8p(const bf16_t* __restrict__ A,
                                                       const bf16_t* __restrict__ BT,
                                                       const float* __restrict__ bo,
                                                       const float* __restrict__ x,
                                                       float* __restrict__ out) {
  extern __shared__ __align__(16) char lds[];
  bf16_t* AS = (bf16_t*)lds;
  bf16_t* BS = AS + 32768;
  const int nwg = gridDim.x, bid = blockIdx.x;
  const int swz = (bid & 7) * (nwg >> 3) + (bid >> 3);
  const int mblk = swz >> 2, nblk = swz & 3;             // N/256 = 4
  const int m0 = mblk * 256, n0 = nblk * 256;
  f32x4 acc[8][4];
#pragma unroll
  for (int i = 0; i < 8; ++i)
#pragma unroll
    for (int j = 0; j < 4; ++j) acc[i][j] = (f32x4){0.f, 0.f, 0.f, 0.f};
  core8p(A + (size_t)m0 * HID, HID, BT + (size_t)n0 * HID, HID,
         HID / 64, AS, BS, acc);

  const int tid = threadIdx.x, wid = tid >> 6, lane = tid & 63;
  const int wm = wid >> 2, wn = wid & 3;
  const int row0 = m0 + wm * 128, col0 = n0 + wn * 64;
#pragma unroll
  for (int mi = 0; mi < 8; ++mi)
#pragma unroll
    for (int nj = 0; nj < 4; ++nj) {
      int col = col0 + nj * 16 + (lane & 15);
      float bv = bo[col];
      int row = row0 + mi * 16 + ((lane >> 4) << 2);
#pragma unroll
      for (int r = 0; r < 4; ++r) {
        size_t gi = (size_t)(row + r) * DIMK + col;
        out[gi] = acc[mi][nj][r] + bv + x[gi];
      }
    }
}

// ---------------------------------------------------------------------------
// 128x128 m97-style core (kept for qk / qkt / pv)
// ---------------------------------------------------------------------------
__device__ __forceinline__ void gemm_core_std(const bf16_t* __restrict__ Ag0, int lda,
                                              const bf16_t* __restrict__ Bg0, int ldb,
                                              int K, bf16_t* As, bf16_t* Bs,
                                              f32x4 acc[4][4]) {
  const int tid = threadIdx.x;
  const int wave = tid >> 6, lane = tid & 63;
  bf16_t* asw = As + wave * 32 * 32;
  bf16_t* bsw = Bs + wave * 32 * 32;
  const int ar = ((wave >> 1) * 64 + (lane & 15)) * 32 + (lane >> 4) * 8;
  const int br = ((wave & 1) * 64 + (lane & 15)) * 32 + (lane >> 4) * 8;
  for (int k0 = 0; k0 < K; k0 += 32) {
    __syncthreads();
    gload_lds16(Ag0 + k0, asw);
    gload_lds16(Ag0 + k0 + 16 * lda, asw + 16 * 32);
    gload_lds16(Bg0 + k0, bsw);
    gload_lds16(Bg0 + k0 + 16 * ldb, bsw + 16 * 32);
    __syncthreads();
    bf16x8 af[4], bfr[4];
#pragma unroll
    for (int m = 0; m < 4; m++) af[m] = *(const bf16x8*)(As + ar + m * 16 * 32);
#pragma unroll
    for (int n = 0; n < 4; n++) bfr[n] = *(const bf16x8*)(Bs + br + n * 16 * 32);
#pragma unroll
    for (int m = 0; m < 4; m++)
#pragma unroll
      for (int n = 0; n < 4; n++) acc[m][n] = MFMA16(af[m], bfr[n], acc[m][n]);
  }
}

// qk GEMM: qkv = silu(normed @ Wqk + bqk); q/k = qkv*gamma+beta (bf16)
__global__ __launch_bounds__(256) void k_gemm_qk(const bf16_t* __restrict__ A,
                                                 const bf16_t* __restrict__ BT,
                                                 const float* __restrict__ bias,
                                                 const float* __restrict__ osg,
                                                 const float* __restrict__ osb,
                                                 bf16_t* __restrict__ qo,
                                                 bf16_t* __restrict__ ko) {
  __shared__ __align__(16) bf16_t As[128 * 32];
  __shared__ __align__(16) bf16_t Bs[128 * 32];
  const int tid = threadIdx.x, wave = tid >> 6, lane = tid & 63;
  const int m0 = blockIdx.y * 128;
  const bf16_t* Ag0 = A + (size_t)(m0 + wave * 32 + (lane >> 2)) * DIMK + (lane & 3) * 8;
  const bf16_t* Bg0 = BT + (size_t)(wave * 32 + (lane >> 2)) * DIMK + (lane & 3) * 8;
  f32x4 acc[4][4];
#pragma unroll
  for (int m = 0; m < 4; m++)
#pragma unroll
    for (int n = 0; n < 4; n++) acc[m][n] = (f32x4){0.f, 0.f, 0.f, 0.f};
  gemm_core_std(Ag0, DIMK, Bg0, DIMK, DIMK, As, Bs, acc);

  const int row0 = m0 + (wave >> 1) * 64;
  const int col0 = (wave & 1) * 64;
#pragma unroll
  for (int m = 0; m < 4; m++) {
#pragma unroll
    for (int n = 0; n < 4; n++) {
      int col = col0 + n * 16 + (lane & 15);
      float bv = bias[col];
      float g0 = osg[col], b0 = osb[col];
      float g1 = osg[QKD + col], b1 = osb[QKD + col];
      int row = row0 + m * 16 + ((lane >> 4) << 2);
#pragma unroll
      for (int r = 0; r < 4; r++) {
        float sv = silu_f(acc[m][n][r] + bv);
        qo[(size_t)(row + r) * QKD + col] = (bf16_t)(sv * g0 + b0);
        ko[(size_t)(row + r) * QKD + col] = (bf16_t)(sv * g1 + b1);
      }
    }
  }
}

// Pass A: P tile (ib,jb) = relu( (q@k^T)/(i+1) )^2, causal, packed-triangular
__global__ __launch_bounds__(256) void k_qkt(const bf16_t* __restrict__ qb,
                                             const bf16_t* __restrict__ kb,
                                             bf16_t* __restrict__ Pb) {
  const int jb = blockIdx.x, ib = blockIdx.y, bb = blockIdx.z;
  if (jb > ib) return;
  __shared__ __align__(16) bf16_t As[128 * 32];
  __shared__ __align__(16) bf16_t Bs[128 * 32];
  const int tid = threadIdx.x, wave = tid >> 6, lane = tid & 63;
  const bf16_t* Ag0 = qb + (size_t)(bb * SEQ + ib * 128 + wave * 32 + (lane >> 2)) * QKD + (lane & 3) * 8;
  const bf16_t* Bg0 = kb + (size_t)(bb * SEQ + jb * 128 + wave * 32 + (lane >> 2)) * QKD + (lane & 3) * 8;
  f32x4 acc[4][4];
#pragma unroll
  for (int m = 0; m < 4; m++)
#pragma unroll
    for (int n = 0; n < 4; n++) acc[m][n] = (f32x4){0.f, 0.f, 0.f, 0.f};
  gemm_core_std(Ag0, QKD, Bg0, QKD, QKD, As, Bs, acc);

  size_t tb = ((size_t)bb * NTILES + (size_t)ib * (ib + 1) / 2 + jb) * 16384;
  const int il0 = (wave >> 1) * 64, jl0 = (wave & 1) * 64;
#pragma unroll
  for (int m = 0; m < 4; m++) {
#pragma unroll
    for (int n = 0; n < 4; n++) {
      int jloc = jl0 + n * 16 + (lane & 15);
      int jg = jb * 128 + jloc;
#pragma unroll
      for (int r = 0; r < 4; r++) {
        int iloc = il0 + m * 16 + ((lane >> 4) << 2) + r;
        int ig = ib * 128 + iloc;
        float sv = acc[m][n][r] / (float)(ig + 1);
        sv = fmaxf(sv, 0.f);
        sv *= sv;
        if (jg > ig) sv = 0.f;
        Pb[tb + (size_t)iloc * 128 + jloc] = (bf16_t)sv;
      }
    }
  }
}

// Pass B: out = P @ v (variable causal K), *= gate in place; heavy-first 1D grid
__global__ __launch_bounds__(256) void k_pv(const bf16_t* __restrict__ Pb,
                                            const bf16_t* __restrict__ vT,
                                            bf16_t* __restrict__ gate) {
  const int w = blockIdx.x;
  const int ib = 31 - (w >> 6);
  const int bb = (w >> 4) & 3;
  const int hb = w & 15;
  const int K = (ib + 1) * 128;
  __shared__ __align__(16) bf16_t As[128 * 32];
  __shared__ __align__(16) bf16_t Bs[128 * 32];
  const int tid = threadIdx.x, wave = tid >> 6, lane = tid & 63;
  bf16_t* asw = As + wave * 32 * 32;
  bf16_t* bsw = Bs + wave * 32 * 32;
  const size_t tb = ((size_t)bb * NTILES + (size_t)ib * (ib + 1) / 2) * 16384;
  const int arow = wave * 32 + (lane >> 2);
  const bf16_t* Bg0 = vT + (size_t)(hb * 128 + wave * 32 + (lane >> 2)) * TOKS + bb * SEQ + (lane & 3) * 8;
  const int ar = ((wave >> 1) * 64 + (lane & 15)) * 32 + (lane >> 4) * 8;
  const int br = ((wave & 1) * 64 + (lane & 15)) * 32 + (lane >> 4) * 8;
  f32x4 acc[4][4];
#pragma unroll
  for (int m = 0; m < 4; m++)
#pragma unroll
    for (int n = 0; n < 4; n++) acc[m][n] = (f32x4){0.f, 0.f, 0.f, 0.f};

  for (int k0 = 0; k0 < K; k0 += 32) {
    __syncthreads();
    const bf16_t* At = Pb + tb + (size_t)(k0 >> 7) * 16384 + (k0 & 127) + (lane & 3) * 8;
    gload_lds16(At + arow * 128, asw);
    gload_lds16(At + (arow + 16) * 128, asw + 16 * 32);
    gload_lds16(Bg0 + k0, bsw);
    gload_lds16(Bg0 + k0 + 16 * TOKS, bsw + 16 * 32);
    __syncthreads();
    bf16x8 af[4], bfr[4];
#pragma unroll
    for (int m = 0; m < 4; m++) af[m] = *(const bf16x8*)(As + ar + m * 16 * 32);
#pragma unroll
    for (int n = 0; n < 4; n++) bfr[n] = *(const bf16x8*)(Bs + br + n * 16 * 32);
#pragma unroll
    for (int m = 0; m < 4; m++)
#pragma unroll
      for (int n = 0; n < 4; n++) acc[m][n] = MFMA16(af[m], bfr[n], acc[m][n]);
  }

  const int row0 = ib * 128 + (wave >> 1) * 64;
  const int col0 = hb * 128 + (wave & 1) * 64;
#pragma unroll
  for (int m = 0; m < 4; m++) {
#pragma unroll
    for (int n = 0; n < 4; n++) {
      int col = col0 + n * 16 + (lane & 15);
      int row = row0 + m * 16 + ((lane >> 4) << 2);
#pragma unroll
      for (int r = 0; r < 4; r++) {
        size_t gi = (size_t)(bb * SEQ + row + r) * HID + col;
        float gv = (float)gate[gi];
        gate[gi] = (bf16_t)(acc[m][n][r] * gv);
      }
    }
  }
}

// ---------------------------------------------------------------------------
extern "C" void kernel_launch(void* const* d_in, const int* in_sizes, int n_in,
                              void* d_out, int out_size, void* d_ws, size_t ws_size,
                              hipStream_t stream) {
  (void)in_sizes; (void)n_in; (void)out_size; (void)ws_size;
  const float* x    = (const float*)d_in[0];
  const float* ln_g = (const float*)d_in[1];
  const float* ln_b = (const float*)d_in[2];
  const float* Wh   = (const float*)d_in[3];
  const float* bh   = (const float*)d_in[4];
  const float* Wqk  = (const float*)d_in[5];
  const float* bqk  = (const float*)d_in[6];
  const float* osg  = (const float*)d_in[7];
  const float* osb  = (const float*)d_in[8];
  const float* Wo   = (const float*)d_in[9];
  const float* bo   = (const float*)d_in[10];
  float* out = (float*)d_out;

  char* ws = (char*)d_ws;
  bf16_t* normed = (bf16_t*)ws;  ws += (size_t)TOKS * DIMK * 2;   // 32 MB
  bf16_t* WhT    = (bf16_t*)ws;  ws += (size_t)H2 * DIMK * 2;     // 8 MB
  bf16_t* WqkT   = (bf16_t*)ws;  ws += (size_t)QKD * DIMK * 2;    // 0.25 MB
  bf16_t* WoT    = (bf16_t*)ws;  ws += (size_t)DIMK * HID * 2;    // 4 MB
  bf16_t* gate   = (bf16_t*)ws;  ws += (size_t)TOKS * HID * 2;    // 64 MB (becomes gated)
  bf16_t* vT     = (bf16_t*)ws;  ws += (size_t)HID * TOKS * 2;    // 64 MB
  bf16_t* qb     = (bf16_t*)ws;  ws += (size_t)TOKS * QKD * 2;    // 4 MB
  bf16_t* kb     = (bf16_t*)ws;  ws += (size_t)TOKS * QKD * 2;    // 4 MB
  bf16_t* Pb     = (bf16_t*)ws;  ws += (size_t)4 * NTILES * 16384 * 2;  // 66 MB

  hipFuncSetAttribute((const void*)k_gemm_hidden8p,
                      hipFuncAttributeMaxDynamicSharedMemorySize, SMEM8P);
  hipFuncSetAttribute((const void*)k_gemm_out8p,
                      hipFuncAttributeMaxDynamicSharedMemorySize, SMEM8P);

  k_transpose_bf16<<<dim3(H2 / 32, DIMK / 32), 256, 0, stream>>>(Wh, WhT, DIMK, H2);
  k_transpose_bf16<<<dim3(QKD / 32, DIMK / 32), 256, 0, stream>>>(Wqk, WqkT, DIMK, QKD);
  k_transpose_bf16<<<dim3(DIMK / 32, HID / 32), 256, 0, stream>>>(Wo, WoT, HID, DIMK);
  k_layernorm<<<TOKS, 256, 0, stream>>>(x, ln_g, ln_b, normed);
  k_gemm_hidden8p<<<dim3((TOKS / 256) * (H2 / 256)), 512, SMEM8P, stream>>>(normed, WhT, bh, vT, gate);
  k_gemm_qk<<<dim3(1, TOKS / 128), 256, 0, stream>>>(normed, WqkT, bqk, osg, osb, qb, kb);
  k_qkt<<<dim3(SEQ / 128, SEQ / 128, 4), 256, 0, stream>>>(qb, kb, Pb);
  k_pv<<<dim3(16 * 32 * 4), 256, 0, stream>>>(Pb, vT, gate);
  k_gemm_out8p<<<dim3((TOKS / 256) * (DIMK / 256)), 512, SMEM8P, stream>>>(gate, WoT, bo, x, out);
}

// Round 5
// 482.705 us; speedup vs baseline: 1.4104x; 1.1141x over previous
//
#include <hip/hip_runtime.h>
#include <hip/hip_bf16.h>
#include <stdint.h>

typedef __bf16 bf16_t;
typedef __bf16 bf16x4 __attribute__((ext_vector_type(4)));
typedef __bf16 bf16x8 __attribute__((ext_vector_type(8)));
typedef float  f32x4  __attribute__((ext_vector_type(4)));

#define MFMA16(a, b, c) __builtin_amdgcn_mfma_f32_16x16x32_bf16((a), (b), (c), 0, 0, 0)

static constexpr int TOKS   = 16384;  // B*N
static constexpr int SEQ    = 4096;
static constexpr int DIMK   = 1024;
static constexpr int H2     = 4096;   // 2*HIDDEN
static constexpr int HID    = 2048;
static constexpr int QKD    = 128;
static constexpr int SMEM8P = 131072; // 2buf x 2half x 128x64 x 2(A,B) x 2B
// P storage: per (batch, rb) rectangular panel [256][(rb+1)*256] bf16
static constexpr size_t PBATCH = 8912896;  // 65536 * 136 elements per batch

// async global->LDS, 16B per lane; LDS dest is wave-uniform base + lane*16 (HW)
__device__ __forceinline__ void gload_lds16(const bf16_t* g, bf16_t* l) {
  __builtin_amdgcn_global_load_lds((__attribute__((address_space(1))) void*)(g),
                                   (__attribute__((address_space(3))) void*)(l),
                                   16, 0, 0);
}

__device__ __forceinline__ float silu_f(float v) { return v / (1.0f + __expf(-v)); }

#define BARRIER() do { __builtin_amdgcn_sched_barrier(0); \
                       __builtin_amdgcn_s_barrier();      \
                       __builtin_amdgcn_sched_barrier(0); } while (0)

// ---------------------------------------------------------------------------
// Weight transpose + f32->bf16:  W[K][N] f32  ->  WT[N][K] bf16
// ---------------------------------------------------------------------------
__global__ __launch_bounds__(256) void k_transpose_bf16(const float* __restrict__ W,
                                                        bf16_t* __restrict__ WT,
                                                        int K, int N) {
  __shared__ float t[32][33];
  int n0 = blockIdx.x * 32, k0 = blockIdx.y * 32;
  int tx = threadIdx.x & 31, ty = threadIdx.x >> 5;  // 32 x 8
#pragma unroll
  for (int r = 0; r < 32; r += 8)
    t[ty + r][tx] = W[(size_t)(k0 + ty + r) * N + n0 + tx];
  __syncthreads();
#pragma unroll
  for (int r = 0; r < 32; r += 8)
    WT[(size_t)(n0 + ty + r) * K + k0 + tx] = (bf16_t)t[tx][ty + r];
}

// ---------------------------------------------------------------------------
// LayerNorm: x[16384][1024] f32 -> normed bf16
// ---------------------------------------------------------------------------
__global__ __launch_bounds__(256) void k_layernorm(const float* __restrict__ x,
                                                   const float* __restrict__ g,
                                                   const float* __restrict__ b,
                                                   bf16_t* __restrict__ out) {
  int row = blockIdx.x, t = threadIdx.x;
  const float4* xr = (const float4*)(x + (size_t)row * DIMK);
  float4 v = xr[t];
  float s  = v.x + v.y + v.z + v.w;
  float ss = v.x * v.x + v.y * v.y + v.z * v.z + v.w * v.w;
#pragma unroll
  for (int o = 1; o < 64; o <<= 1) { s += __shfl_xor(s, o); ss += __shfl_xor(ss, o); }
  __shared__ float red[8];
  int wave = t >> 6, lane = t & 63;
  if (lane == 0) { red[wave] = s; red[wave + 4] = ss; }
  __syncthreads();
  s  = red[0] + red[1] + red[2] + red[3];
  ss = red[4] + red[5] + red[6] + red[7];
  float mean = s * (1.0f / DIMK);
  float var  = ss * (1.0f / DIMK) - mean * mean;
  float rstd = rsqrtf(var + 1e-5f);
  float4 gg = ((const float4*)g)[t];
  float4 bb = ((const float4*)b)[t];
  bf16x4 o4;
  o4[0] = (bf16_t)((v.x - mean) * rstd * gg.x + bb.x);
  o4[1] = (bf16_t)((v.y - mean) * rstd * gg.y + bb.y);
  o4[2] = (bf16_t)((v.z - mean) * rstd * gg.z + bb.z);
  o4[3] = (bf16_t)((v.w - mean) * rstd * gg.w + bb.w);
  *(bf16x4*)(out + (size_t)row * DIMK + t * 4) = o4;
}

// ---------------------------------------------------------------------------
// 8-phase 256x256 GEMM core (m201-style). 512 thr / 8 waves (2M x 4N), BK=64.
// See r3/r4 notes: per group g (K-tile), 4 phases of
// {ds_read quadrant ∥ stage half-tile ∥ BAR ∥ 16 MFMA ∥ BAR}; counted
// vmcnt(4) once per group, vmcnt(0) only at g=NK-2. Read-side XOR swizzle
// with pre-swizzled global source (both-sides rule).
// ---------------------------------------------------------------------------
#define MFMAQ(MH, KK)                                                         \
  _Pragma("unroll")                                                           \
  for (int mi = 0; mi < 4; ++mi)                                              \
    _Pragma("unroll")                                                         \
    for (int nj = 0; nj < 4; ++nj)                                            \
      acc[(MH) * 4 + mi][nj] =                                                \
          MFMA16(aF[(MH) * 4 + mi][KK], bF[nj][KK], acc[(MH) * 4 + mi][nj]);

__device__ __forceinline__ void core8p(const bf16_t* __restrict__ Ag, int lda,
                                       const bf16_t* __restrict__ Bg, int ldb,
                                       int NK, bf16_t* AS, bf16_t* BS,
                                       f32x4 (&acc)[8][4]) {
  const int tid = threadIdx.x, wid = tid >> 6, lane = tid & 63;
  const int wm = wid >> 2, wn = wid & 3;
  const int srow = lane >> 3;                 // row within 8-row chunk
  const int scol = ((lane & 7) ^ srow) * 8;   // pre-swizzled source column

  auto stA = [&](int kt, int h) {
    const bf16_t* s = Ag + (size_t)(h * 128 + wid * 16 + srow) * lda + kt * 64 + scol;
    bf16_t* d = AS + ((kt & 1) * 2 + h) * 8192 + wid * 1024;
    gload_lds16(s, d);
    gload_lds16(s + 8 * lda, d + 512);
  };
  auto stB = [&](int kt, int h) {
    const bf16_t* s = Bg + (size_t)(h * 128 + wid * 16 + srow) * ldb + kt * 64 + scol;
    bf16_t* d = BS + ((kt & 1) * 2 + h) * 8192 + wid * 1024;
    gload_lds16(s, d);
    gload_lds16(s + 8 * ldb, d + 512);
  };

  const int g0 = (lane >> 4) ^ (lane & 7);
  const bf16_t* pA0 = AS + wm * 8192 + (lane & 15) * 64 + g0 * 8;
  const bf16_t* pA1 = AS + wm * 8192 + (lane & 15) * 64 + (g0 ^ 4) * 8;
  const bf16_t* pB0 = BS + (wn >> 1) * 8192 + ((wn & 1) * 64 + (lane & 15)) * 64 + g0 * 8;
  const bf16_t* pB1 = BS + (wn >> 1) * 8192 + ((wn & 1) * 64 + (lane & 15)) * 64 + (g0 ^ 4) * 8;

  bf16x8 aF[8][2], bF[4][2];

  // prologue: kt0 fully + kt1 A-halves (NK >= 2 required)
  stA(0, 0); stA(0, 1); stB(0, 0); stB(0, 1);
  stA(1, 0); stA(1, 1);
  asm volatile("s_waitcnt vmcnt(4)" ::: "memory");
  BARRIER();

  for (int g = 0; g < NK; ++g) {
    const int buf = (g & 1) * 16384;
    // ---- p0
#pragma unroll
    for (int mi = 0; mi < 8; ++mi) aF[mi][0] = *(const bf16x8*)(pA0 + buf + mi * 1024);
#pragma unroll
    for (int nj = 0; nj < 4; ++nj) bF[nj][0] = *(const bf16x8*)(pB0 + buf + nj * 1024);
    if (g + 1 < NK) stB(g + 1, 0);
    BARRIER();
    __builtin_amdgcn_s_setprio(1);
    MFMAQ(0, 0);
    __builtin_amdgcn_s_setprio(0);
    BARRIER();
    // ---- p1
#pragma unroll
    for (int mi = 0; mi < 8; ++mi) aF[mi][1] = *(const bf16x8*)(pA1 + buf + mi * 1024);
    if (g + 1 < NK) stB(g + 1, 1);
    BARRIER();
    __builtin_amdgcn_s_setprio(1);
    MFMAQ(1, 0);
    __builtin_amdgcn_s_setprio(0);
    BARRIER();
    // ---- p2
#pragma unroll
    for (int nj = 0; nj < 4; ++nj) bF[nj][1] = *(const bf16x8*)(pB1 + buf + nj * 1024);
    if (g + 2 < NK) stA(g + 2, 0);
    BARRIER();
    __builtin_amdgcn_s_setprio(1);
    MFMAQ(0, 1);
    __builtin_amdgcn_s_setprio(0);
    BARRIER();
    // ---- p3
    if (g + 2 < NK) stA(g + 2, 1);
    BARRIER();
    __builtin_amdgcn_s_setprio(1);
    MFMAQ(1, 1);
    __builtin_amdgcn_s_setprio(0);
    if (g < NK - 2)       { asm volatile("s_waitcnt vmcnt(4)" ::: "memory"); }
    else if (g == NK - 2) { asm volatile("s_waitcnt vmcnt(0)" ::: "memory"); }
    BARRIER();
  }
}

// GEMM1 on 8-phase core: silu(normed @ Wh + bh) -> vT (transposed) / gate
__global__ __launch_bounds__(512, 2) void k_gemm_hidden8p(const bf16_t* __restrict__ A,
                                                          const bf16_t* __restrict__ BT,
                                                          const float* __restrict__ bias,
                                                          bf16_t* __restrict__ vT,
                                                          bf16_t* __restrict__ gate) {
  extern __shared__ __align__(16) char lds[];
  bf16_t* AS = (bf16_t*)lds;
  bf16_t* BS = AS + 32768;
  const int nwg = gridDim.x, bid = blockIdx.x;
  const int swz = (bid & 7) * (nwg >> 3) + (bid >> 3);   // XCD-contiguous
  const int mblk = swz >> 4, nblk = swz & 15;            // N/256 = 16
  const int m0 = mblk * 256, n0 = nblk * 256;
  f32x4 acc[8][4];
#pragma unroll
  for (int i = 0; i < 8; ++i)
#pragma unroll
    for (int j = 0; j < 4; ++j) acc[i][j] = (f32x4){0.f, 0.f, 0.f, 0.f};
  core8p(A + (size_t)m0 * DIMK, DIMK, BT + (size_t)n0 * DIMK, DIMK,
         DIMK / 64, AS, BS, acc);

  const int tid = threadIdx.x, wid = tid >> 6, lane = tid & 63;
  const int wm = wid >> 2, wn = wid & 3;
  const int row0 = m0 + wm * 128, col0 = n0 + wn * 64;
#pragma unroll
  for (int mi = 0; mi < 8; ++mi)
#pragma unroll
    for (int nj = 0; nj < 4; ++nj) {
      int col = col0 + nj * 16 + (lane & 15);
      float bv = bias[col];
      int row = row0 + mi * 16 + ((lane >> 4) << 2);
      float sv[4];
#pragma unroll
      for (int r = 0; r < 4; ++r) sv[r] = silu_f(acc[mi][nj][r] + bv);
      if (col < HID) {
        bf16x4 pk;
#pragma unroll
        for (int r = 0; r < 4; ++r) pk[r] = (bf16_t)sv[r];
        *(bf16x4*)(vT + (size_t)col * TOKS + row) = pk;
      } else {
#pragma unroll
        for (int r = 0; r < 4; ++r)
          gate[(size_t)(row + r) * HID + (col - HID)] = (bf16_t)sv[r];
      }
    }
}

// Final GEMM on 8-phase core: out = gated @ Wo + bo + x (fp32 out + residual)
__global__ __launch_bounds__(512, 2) void k_gemm_out8p(const bf16_t* __restrict__ A,
                                                       const bf16_t* __restrict__ BT,
                                                       const float* __restrict__ bo,
                                                       const float* __restrict__ x,
                                                       float* __restrict__ out) {
  extern __shared__ __align__(16) char lds[];
  bf16_t* AS = (bf16_t*)lds;
  bf16_t* BS = AS + 32768;
  const int nwg = gridDim.x, bid = blockIdx.x;
  const int swz = (bid & 7) * (nwg >> 3) + (bid >> 3);
  const int mblk = swz >> 2, nblk = swz & 3;             // N/256 = 4
  const int m0 = mblk * 256, n0 = nblk * 256;
  f32x4 acc[8][4];
#pragma unroll
  for (int i = 0; i < 8; ++i)
#pragma unroll
    for (int j = 0; j < 4; ++j) acc[i][j] = (f32x4){0.f, 0.f, 0.f, 0.f};
  core8p(A + (size_t)m0 * HID, HID, BT + (size_t)n0 * HID, HID,
         HID / 64, AS, BS, acc);

  const int tid = threadIdx.x, wid = tid >> 6, lane = tid & 63;
  const int wm = wid >> 2, wn = wid & 3;
  const int row0 = m0 + wm * 128, col0 = n0 + wn * 64;
#pragma unroll
  for (int mi = 0; mi < 8; ++mi)
#pragma unroll
    for (int nj = 0; nj < 4; ++nj) {
      int col = col0 + nj * 16 + (lane & 15);
      float bv = bo[col];
      int row = row0 + mi * 16 + ((lane >> 4) << 2);
#pragma unroll
      for (int r = 0; r < 4; ++r) {
        size_t gi = (size_t)(row + r) * DIMK + col;
        out[gi] = acc[mi][nj][r] + bv + x[gi];
      }
    }
}

// PV on 8-phase core: out = P @ v (rect causal panels), *= gate in place.
// Heavy-first 1D grid: rb descending; greedy CU reuse pairs (rb1+1)+(rb2+1)=17
// -> near-uniform makespan. K = (rb+1)*256, NK = (rb+1)*4 >= 4.
__global__ __launch_bounds__(512, 2) void k_pv8p(const bf16_t* __restrict__ Pb,
                                                 const bf16_t* __restrict__ vT,
                                                 bf16_t* __restrict__ gate) {
  extern __shared__ __align__(16) char lds[];
  bf16_t* AS = (bf16_t*)lds;
  bf16_t* BS = AS + 32768;
  const int w = blockIdx.x;
  const int rb = 15 - (w >> 5);
  const int hb = (w >> 2) & 7;
  const int bb = w & 3;
  const int lda = (rb + 1) * 256;
  const bf16_t* Ag = Pb + (size_t)bb * PBATCH + (size_t)65536 * (rb * (rb + 1) / 2);
  const bf16_t* Bg = vT + (size_t)(hb * 256) * TOKS + (size_t)bb * SEQ;
  f32x4 acc[8][4];
#pragma unroll
  for (int i = 0; i < 8; ++i)
#pragma unroll
    for (int j = 0; j < 4; ++j) acc[i][j] = (f32x4){0.f, 0.f, 0.f, 0.f};
  core8p(Ag, lda, Bg, TOKS, (rb + 1) * 4, AS, BS, acc);

  const int tid = threadIdx.x, wid = tid >> 6, lane = tid & 63;
  const int wm = wid >> 2, wn = wid & 3;
  const int row0 = rb * 256 + wm * 128, col0 = hb * 256 + wn * 64;
#pragma unroll
  for (int mi = 0; mi < 8; ++mi)
#pragma unroll
    for (int nj = 0; nj < 4; ++nj) {
      int col = col0 + nj * 16 + (lane & 15);
      int row = row0 + mi * 16 + ((lane >> 4) << 2);
#pragma unroll
      for (int r = 0; r < 4; ++r) {
        size_t gi = (size_t)(bb * SEQ + row + r) * HID + col;
        float gv = (float)gate[gi];
        gate[gi] = (bf16_t)(acc[mi][nj][r] * gv);
      }
    }
}

// ---------------------------------------------------------------------------
// 128x128 m97-style core (kept for qk / qkt)
// ---------------------------------------------------------------------------
__device__ __forceinline__ void gemm_core_std(const bf16_t* __restrict__ Ag0, int lda,
                                              const bf16_t* __restrict__ Bg0, int ldb,
                                              int K, bf16_t* As, bf16_t* Bs,
                                              f32x4 acc[4][4]) {
  const int tid = threadIdx.x;
  const int wave = tid >> 6, lane = tid & 63;
  bf16_t* asw = As + wave * 32 * 32;
  bf16_t* bsw = Bs + wave * 32 * 32;
  const int ar = ((wave >> 1) * 64 + (lane & 15)) * 32 + (lane >> 4) * 8;
  const int br = ((wave & 1) * 64 + (lane & 15)) * 32 + (lane >> 4) * 8;
  for (int k0 = 0; k0 < K; k0 += 32) {
    __syncthreads();
    gload_lds16(Ag0 + k0, asw);
    gload_lds16(Ag0 + k0 + 16 * lda, asw + 16 * 32);
    gload_lds16(Bg0 + k0, bsw);
    gload_lds16(Bg0 + k0 + 16 * ldb, bsw + 16 * 32);
    __syncthreads();
    bf16x8 af[4], bfr[4];
#pragma unroll
    for (int m = 0; m < 4; m++) af[m] = *(const bf16x8*)(As + ar + m * 16 * 32);
#pragma unroll
    for (int n = 0; n < 4; n++) bfr[n] = *(const bf16x8*)(Bs + br + n * 16 * 32);
#pragma unroll
    for (int m = 0; m < 4; m++)
#pragma unroll
      for (int n = 0; n < 4; n++) acc[m][n] = MFMA16(af[m], bfr[n], acc[m][n]);
  }
}

// qk GEMM: qkv = silu(normed @ Wqk + bqk); q/k = qkv*gamma+beta (bf16)
__global__ __launch_bounds__(256) void k_gemm_qk(const bf16_t* __restrict__ A,
                                                 const bf16_t* __restrict__ BT,
                                                 const float* __restrict__ bias,
                                                 const float* __restrict__ osg,
                                                 const float* __restrict__ osb,
                                                 bf16_t* __restrict__ qo,
                                                 bf16_t* __restrict__ ko) {
  __shared__ __align__(16) bf16_t As[128 * 32];
  __shared__ __align__(16) bf16_t Bs[128 * 32];
  const int tid = threadIdx.x, wave = tid >> 6, lane = tid & 63;
  const int m0 = blockIdx.y * 128;
  const bf16_t* Ag0 = A + (size_t)(m0 + wave * 32 + (lane >> 2)) * DIMK + (lane & 3) * 8;
  const bf16_t* Bg0 = BT + (size_t)(wave * 32 + (lane >> 2)) * DIMK + (lane & 3) * 8;
  f32x4 acc[4][4];
#pragma unroll
  for (int m = 0; m < 4; m++)
#pragma unroll
    for (int n = 0; n < 4; n++) acc[m][n] = (f32x4){0.f, 0.f, 0.f, 0.f};
  gemm_core_std(Ag0, DIMK, Bg0, DIMK, DIMK, As, Bs, acc);

  const int row0 = m0 + (wave >> 1) * 64;
  const int col0 = (wave & 1) * 64;
#pragma unroll
  for (int m = 0; m < 4; m++) {
#pragma unroll
    for (int n = 0; n < 4; n++) {
      int col = col0 + n * 16 + (lane & 15);
      float bv = bias[col];
      float g0 = osg[col], b0 = osb[col];
      float g1 = osg[QKD + col], b1 = osb[QKD + col];
      int row = row0 + m * 16 + ((lane >> 4) << 2);
#pragma unroll
      for (int r = 0; r < 4; r++) {
        float sv = silu_f(acc[m][n][r] + bv);
        qo[(size_t)(row + r) * QKD + col] = (bf16_t)(sv * g0 + b0);
        ko[(size_t)(row + r) * QKD + col] = (bf16_t)(sv * g1 + b1);
      }
    }
  }
}

// Pass A: P tile (ib,jb) = relu( (q@k^T)/(i+1) )^2, causal, written into the
// rectangular per-(bb,rb) panels [256][(rb+1)*256]. For even ib the jb=ib+1
// tile is fully masked -> written as zeros (block-uniform branch).
__global__ __launch_bounds__(256) void k_qkt(const bf16_t* __restrict__ qb,
                                             const bf16_t* __restrict__ kb,
                                             bf16_t* __restrict__ Pb) {
  const int jb = blockIdx.x, ib = blockIdx.y, bb = blockIdx.z;
  const int rb = ib >> 1;
  if (jb > 2 * rb + 1) return;
  const int lda = (rb + 1) * 256;
  bf16_t* Pt = Pb + (size_t)bb * PBATCH + (size_t)65536 * (rb * (rb + 1) / 2)
             + (size_t)((ib & 1) * 128) * lda + jb * 128;
  if (jb == ib + 1) {  // ib even: fully above-diagonal tile -> zeros
    const int row = threadIdx.x >> 1, cb = (threadIdx.x & 1) * 64;
    bf16x8 z;
#pragma unroll
    for (int i = 0; i < 8; ++i) z[i] = (bf16_t)0.0f;
#pragma unroll
    for (int c = 0; c < 64; c += 8)
      *(bf16x8*)(Pt + (size_t)row * lda + cb + c) = z;
    return;
  }
  __shared__ __align__(16) bf16_t As[128 * 32];
  __shared__ __align__(16) bf16_t Bs[128 * 32];
  const int tid = threadIdx.x, wave = tid >> 6, lane = tid & 63;
  const bf16_t* Ag0 = qb + (size_t)(bb * SEQ + ib * 128 + wave * 32 + (lane >> 2)) * QKD + (lane & 3) * 8;
  const bf16_t* Bg0 = kb + (size_t)(bb * SEQ + jb * 128 + wave * 32 + (lane >> 2)) * QKD + (lane & 3) * 8;
  f32x4 acc[4][4];
#pragma unroll
  for (int m = 0; m < 4; m++)
#pragma unroll
    for (int n = 0; n < 4; n++) acc[m][n] = (f32x4){0.f, 0.f, 0.f, 0.f};
  gemm_core_std(Ag0, QKD, Bg0, QKD, QKD, As, Bs, acc);

  const int il0 = (wave >> 1) * 64, jl0 = (wave & 1) * 64;
#pragma unroll
  for (int m = 0; m < 4; m++) {
#pragma unroll
    for (int n = 0; n < 4; n++) {
      int jloc = jl0 + n * 16 + (lane & 15);
      int jg = jb * 128 + jloc;
#pragma unroll
      for (int r = 0; r < 4; r++) {
        int iloc = il0 + m * 16 + ((lane >> 4) << 2) + r;
        int ig = ib * 128 + iloc;
        float sv = acc[m][n][r] / (float)(ig + 1);
        sv = fmaxf(sv, 0.f);
        sv *= sv;
        if (jg > ig) sv = 0.f;
        Pt[(size_t)iloc * lda + jloc] = (bf16_t)sv;
      }
    }
  }
}

// ---------------------------------------------------------------------------
extern "C" void kernel_launch(void* const* d_in, const int* in_sizes, int n_in,
                              void* d_out, int out_size, void* d_ws, size_t ws_size,
                              hipStream_t stream) {
  (void)in_sizes; (void)n_in; (void)out_size; (void)ws_size;
  const float* x    = (const float*)d_in[0];
  const float* ln_g = (const float*)d_in[1];
  const float* ln_b = (const float*)d_in[2];
  const float* Wh   = (const float*)d_in[3];
  const float* bh   = (const float*)d_in[4];
  const float* Wqk  = (const float*)d_in[5];
  const float* bqk  = (const float*)d_in[6];
  const float* osg  = (const float*)d_in[7];
  const float* osb  = (const float*)d_in[8];
  const float* Wo   = (const float*)d_in[9];
  const float* bo   = (const float*)d_in[10];
  float* out = (float*)d_out;

  char* ws = (char*)d_ws;
  bf16_t* normed = (bf16_t*)ws;  ws += (size_t)TOKS * DIMK * 2;   // 32 MB
  bf16_t* WhT    = (bf16_t*)ws;  ws += (size_t)H2 * DIMK * 2;     // 8 MB
  bf16_t* WqkT   = (bf16_t*)ws;  ws += (size_t)QKD * DIMK * 2;    // 0.25 MB
  bf16_t* WoT    = (bf16_t*)ws;  ws += (size_t)DIMK * HID * 2;    // 4 MB
  bf16_t* gate   = (bf16_t*)ws;  ws += (size_t)TOKS * HID * 2;    // 64 MB (becomes gated)
  bf16_t* vT     = (bf16_t*)ws;  ws += (size_t)HID * TOKS * 2;    // 64 MB
  bf16_t* qb     = (bf16_t*)ws;  ws += (size_t)TOKS * QKD * 2;    // 4 MB
  bf16_t* kb     = (bf16_t*)ws;  ws += (size_t)TOKS * QKD * 2;    // 4 MB
  bf16_t* Pb     = (bf16_t*)ws;  ws += (size_t)4 * PBATCH * 2;    // 71.3 MB

  hipFuncSetAttribute((const void*)k_gemm_hidden8p,
                      hipFuncAttributeMaxDynamicSharedMemorySize, SMEM8P);
  hipFuncSetAttribute((const void*)k_gemm_out8p,
                      hipFuncAttributeMaxDynamicSharedMemorySize, SMEM8P);
  hipFuncSetAttribute((const void*)k_pv8p,
                      hipFuncAttributeMaxDynamicSharedMemorySize, SMEM8P);

  k_transpose_bf16<<<dim3(H2 / 32, DIMK / 32), 256, 0, stream>>>(Wh, WhT, DIMK, H2);
  k_transpose_bf16<<<dim3(QKD / 32, DIMK / 32), 256, 0, stream>>>(Wqk, WqkT, DIMK, QKD);
  k_transpose_bf16<<<dim3(DIMK / 32, HID / 32), 256, 0, stream>>>(Wo, WoT, HID, DIMK);
  k_layernorm<<<TOKS, 256, 0, stream>>>(x, ln_g, ln_b, normed);
  k_gemm_hidden8p<<<dim3((TOKS / 256) * (H2 / 256)), 512, SMEM8P, stream>>>(normed, WhT, bh, vT, gate);
  k_gemm_qk<<<dim3(1, TOKS / 128), 256, 0, stream>>>(normed, WqkT, bqk, osg, osb, qb, kb);
  k_qkt<<<dim3(SEQ / 128, SEQ / 128, 4), 256, 0, stream>>>(qb, kb, Pb);
  k_pv8p<<<dim3(16 * 8 * 4), 512, SMEM8P, stream>>>(Pb, vT, gate);
  k_gemm_out8p<<<dim3((TOKS / 256) * (DIMK / 256)), 512, SMEM8P, stream>>>(gate, WoT, bo, x, out);
}